// Round 5
// baseline (1830.439 us; speedup 1.0000x reference)
//
#include <hip/hip_runtime.h>
#include <hip/hip_bf16.h>

#define THREADS 576

typedef __hip_bfloat16 bf16;
typedef __attribute__((ext_vector_type(4))) float f32x4;
typedef __attribute__((ext_vector_type(8))) short bf16x8;

#define MFMA __builtin_amdgcn_mfma_f32_16x16x32_bf16

// ---- LDS layout (bf16 elems). Per-stream stride SSTR; blocks of 512 = one 16x32 tile
#define SSTR  38912
#define O_A1  0       // 2 slots x 4mt : [x(2)|h1(16)|pad14]
#define O_AY  4096    // 2 slots x 4mt x 2kc : [y(36)|pad]
#define O_AT1 12288   // 4mt x 2kc : t1(64)
#define O_A2  16384   // 4mt x 9kc : [l2(72)|pad24 | h2 slot0 (3kc) | h2 slot1 (3kc)]
#define O_AH3 34816   // 2 slots x 4mt : h3(32)
#define LDS_ELEMS (2 * SSTR)
#define LDS_BYTES (LDS_ELEMS * 2)   // 155648

// self-consistent K mapping within a 16x32 fragment tile (verified round 1)
__device__ __forceinline__ int kmap(int l, int j) {
    return (((l >> 4) & 3) << 2) + (j & 3) + ((j >> 2) << 4);
}
__device__ __forceinline__ int frag_off(int m, int k) { // k in [0,32)
    int l = (m & 15) | (((k >> 2) & 3) << 4);
    int j = (k & 3) | (((k >> 4) & 1) << 2);
    return (l << 3) + j;
}
__device__ __forceinline__ void st_frag(bf16* sbase, int KC, int m, int k, float v) {
    sbase[(((m >> 4) * KC + (k >> 5)) << 9) + frag_off(m, k & 31)] = __float2bfloat16(v);
}

__device__ __forceinline__ float rcp_(float x) { return __builtin_amdgcn_rcpf(x); }
__device__ __forceinline__ float sigm(float x) { return rcp_(1.0f + __expf(-x)); }
__device__ __forceinline__ float tanh_(float x) { return 1.0f - 2.0f * rcp_(1.0f + __expf(2.0f * x)); }

__device__ __forceinline__ float pick4(float a, float b, float c, float d, int j) {
    float ab = (j & 1) ? b : a;
    float cd = (j & 1) ? d : c;
    return (j & 2) ? cd : ab;
}

// DPP lane permute (VALU, no DS op). quad xor1=0xB1, xor2=0x4E, xor3=0x1B; row_ror4=0x124, ror8=0x128
template <int CTRL>
__device__ __forceinline__ float qperm(float v) {
    return __int_as_float(__builtin_amdgcn_mov_dpp(__float_as_int(v), CTRL, 0xF, 0xF, true));
}

__device__ __forceinline__ ushort bfu(float f) {
    union { bf16 b; ushort u; } v; v.b = __float2bfloat16(f); return v.u;
}

// fused gate-EW for interleaved-gate tiles: col n = h*4+g ; lane (g=lane&3) does row base+g
template <typename WR>
__device__ __forceinline__ void lstm_tile_ew(f32x4 acc, float bias, float& cst, int lane, WR wr) {
    int g = lane & 3;
    float a0 = acc[0] + bias, a1 = acc[1] + bias, a2 = acc[2] + bias, a3 = acc[3] + bias;
    float own = pick4(a0, a1, a2, a3, g);
    float p1 = pick4(a0, a1, a2, a3, g ^ 1);
    float p2 = pick4(a0, a1, a2, a3, g ^ 2);
    float p3 = pick4(a0, a1, a2, a3, g ^ 3);
    float q1 = qperm<0xB1>(p1);
    float q2 = qperm<0x4E>(p2);
    float q3 = qperm<0x1B>(p3);
    float iv = pick4(own, q1, q2, q3, g);
    float fv = pick4(own, q1, q2, q3, g ^ 1);
    float gv = pick4(own, q1, q2, q3, g ^ 2);
    float ov = pick4(own, q1, q2, q3, g ^ 3);
    float c = sigm(fv) * cst + sigm(iv) * tanh_(gv);
    cst = c;
    wr(sigm(ov) * tanh_(c));
}

template <typename F>
__device__ __forceinline__ bf16x8 mk_frag(int lane, F val) { // val(k), k in [0,32)
    union { bf16x8 v; bf16 h[8]; } u;
#pragma unroll
    for (int j = 0; j < 8; ++j) u.h[j] = __float2bfloat16(val(kmap(lane, j)));
    return u.v;
}

__global__ void __launch_bounds__(THREADS)
lstm_fused(const float* __restrict__ x, const float* __restrict__ y,
           const float* __restrict__ Wih1, const float* __restrict__ Whh1,
           const float* __restrict__ bih1, const float* __restrict__ bhh1,
           const float* __restrict__ Wih2, const float* __restrict__ Whh2,
           const float* __restrict__ bih2, const float* __restrict__ bhh2,
           const float* __restrict__ Wih3, const float* __restrict__ Whh3,
           const float* __restrict__ bih3, const float* __restrict__ bhh3,
           const float* __restrict__ W1, const float* __restrict__ b1,
           const float* __restrict__ W2, const float* __restrict__ b2,
           const float* __restrict__ W3, const float* __restrict__ b3,
           const float* __restrict__ W4, const float* __restrict__ b4,
           float* __restrict__ out) {
    extern __shared__ char smem[];
    bf16* sb = (bf16*)smem;
    const int tid = threadIdx.x;
    const int wave = tid >> 6, lane = tid & 63, ln15 = lane & 15;
    const int b0 = blockIdx.x * 128;

    // ---- per-wave register-resident B fragments + biases (shared by both streams) ----
    bf16x8 bL1 = {};  float biasL1 = 0.f;
    bf16x8 bF1[2] = {}; float biasF1 = 0.f;
    bf16x8 bF2[2] = {}; float biasF2 = 0.f;
    bf16x8 bL2[2][6]; float biasL2[2];
    bf16x8 bL3[5] = {}; float biasL3 = 0.f;
    bf16x8 bF3 = {};  float biasF3 = 0.f, w40 = 0.f, w41 = 0.f, b40 = 0.f, b41 = 0.f;

    if (wave < 4) { // LSTM1 gates interleaved: nt=wave, H=16
        int n = (wave << 4) + ln15;
        int r = (n & 3) * 16 + (n >> 2);
        biasL1 = bih1[r] + bhh1[r];
        bL1 = mk_frag(lane, [&](int k) {
            return k < 2 ? Wih1[r * 2 + k] : (k < 18 ? Whh1[r * 16 + (k - 2)] : 0.0f); });
    }
    if (wave >= 4 && wave < 8) { // FC1: nt=wave-4
        int n = ((wave - 4) << 4) + ln15;
        biasF1 = b1[n];
#pragma unroll
        for (int kc = 0; kc < 2; ++kc)
            bF1[kc] = mk_frag(lane, [&](int kl) {
                int k = kc * 32 + kl; return k < 36 ? W1[n * 36 + k] : 0.0f; });
    }
    if (wave < 5) { // FC2: nt=wave, 72 cols
        int n = (wave << 4) + ln15;
        biasF2 = (n < 72) ? b2[n] : 0.0f;
#pragma unroll
        for (int kc = 0; kc < 2; ++kc)
            bF2[kc] = mk_frag(lane, [&](int kl) {
                int k = kc * 32 + kl; return (n < 72) ? W2[n * 64 + k] : 0.0f; });
    }
#pragma unroll
    for (int ntl = 0; ntl < 2; ++ntl) { // LSTM2 interleaved: nt = wave + ntl*9, H=72
        int n = ((wave + ntl * 9) << 4) + ln15;
        int r = (n & 3) * 72 + (n >> 2);
        biasL2[ntl] = bih2[r] + bhh2[r];
#pragma unroll
        for (int b = 0; b < 6; ++b)
            bL2[ntl][b] = mk_frag(lane, [&](int kl) {
                if (b < 3) { int k = b * 32 + kl; return k < 72 ? Wih2[r * 72 + k] : 0.0f; }
                int k = (b - 3) * 32 + kl; return k < 72 ? Whh2[r * 72 + k] : 0.0f; });
    }
    if (wave < 8) { // LSTM3 interleaved: nt=wave, H=32
        int n = (wave << 4) + ln15;
        int r = (n & 3) * 32 + (n >> 2);
        biasL3 = bih3[r] + bhh3[r];
        // b0 <- A1 tile [x(2)|h1(16)|pad14] ; b1..3 <- A2 h2 slots ; b4 <- AH3 h3
        bL3[0] = mk_frag(lane, [&](int k) {
            return (k >= 2 && k < 18) ? Wih3[r * 88 + (k - 2)] : 0.0f; });
#pragma unroll
        for (int j = 0; j < 3; ++j)
            bL3[1 + j] = mk_frag(lane, [&](int kl) {
                int h2 = j * 32 + kl; return h2 < 72 ? Wih3[r * 88 + 16 + h2] : 0.0f; });
        bL3[4] = mk_frag(lane, [&](int k) { return Whh3[r * 32 + k]; });
    }
    if (wave >= 5) { // FC3 (mt=wave-5) + FC4 scalars
        int n3 = ln15;
        biasF3 = b3[n3]; w40 = W4[n3]; w41 = W4[16 + n3];
        b40 = b4[0]; b41 = b4[1];
        bF3 = mk_frag(lane, [&](int k) { return W3[n3 * 32 + k]; });
    }

    // ---- zero LDS ----
    {
        int4* z = (int4*)sb;
        int4 zv = {0, 0, 0, 0};
        for (int i = tid; i < LDS_BYTES / 16; i += THREADS) z[i] = zv;
    }
    __syncthreads();
    // ---- stage x(0), y(0) for both streams (into slot 0) ----
    if (tid < 256) {
        int s = tid >> 7, m = (tid >> 1) & 63, k = tid & 1;
        st_frag(sb + s * SSTR + O_A1, 1, m, k, x[(size_t)(b0 + s * 64 + m) * 50 + k]);
    }
    for (int it = tid; it < 2 * 64 * 36; it += THREADS) {
        int s = it / 2304, r2 = it - s * 2304;
        int m = r2 / 36, k = r2 - m * 36;
        st_frag(sb + s * SSTR + O_AY, 2, m, k, y[(size_t)(b0 + s * 64 + m) * 900 + k]);
    }
    float c1[2][4] = {};
    float c2[2][2][4] = {};
    float c3[2][4] = {};
    __syncthreads();

    for (int t = 0; t < 25; ++t) {
        const int rs = t & 1, ws = rs ^ 1;

        // ---- P1: LSTM1 (w0-3) | FC1 (w4-7) | y/x(t+1) load+stage (w8) ----
        if (wave < 4) {
#pragma unroll
            for (int s = 0; s < 2; ++s) {
                bf16* base = sb + s * SSTR;
#pragma unroll
                for (int mt = 0; mt < 4; ++mt) {
                    bf16x8 a = *(const bf16x8*)(base + O_A1 + ((rs * 4 + mt) << 9) + (lane << 3));
                    f32x4 acc = {0.f, 0.f, 0.f, 0.f};
                    acc = MFMA(a, bL1, acc, 0, 0, 0);
                    lstm_tile_ew(acc, biasL1, c1[s][mt], lane, [&](float hv) {
                        int m = (mt << 4) + ((lane >> 4) << 2) + (lane & 3);
                        int h = (wave << 2) + ((lane >> 2) & 3);
                        st_frag(base + O_A1 + ((ws * 4) << 9), 1, m, 2 + h, hv);
                    });
                }
            }
        } else if (wave < 8) {
            const int nt = wave - 4;
#pragma unroll
            for (int s = 0; s < 2; ++s) {
                bf16* base = sb + s * SSTR;
#pragma unroll
                for (int mt = 0; mt < 4; ++mt) {
                    f32x4 acc = {0.f, 0.f, 0.f, 0.f};
#pragma unroll
                    for (int kc = 0; kc < 2; ++kc) {
                        bf16x8 a = *(const bf16x8*)(base + O_AY + ((rs * 8 + mt * 2 + kc) << 9) + (lane << 3));
                        acc = MFMA(a, bF1[kc], acc, 0, 0, 0);
                    }
                    int n = (nt << 4) + ln15;
                    int mrow = (mt << 4) + ((lane >> 4) << 2);
#pragma unroll
                    for (int r = 0; r < 4; ++r)
                        st_frag(base + O_AT1, 2, mrow + r, n, fmaxf(acc[r] + biasF1, 0.0f));
                }
            }
        } else if (t < 24) {
#pragma unroll
            for (int s = 0; s < 2; ++s) {
                bf16* base = sb + s * SSTR;
                const int m = lane, mt = m >> 4;
                const float* yp = y + (size_t)(b0 + s * 64 + m) * 900 + (t + 1) * 36;
                float4 yv[9];
#pragma unroll
                for (int c = 0; c < 9; ++c) yv[c] = *(const float4*)(yp + c * 4);
                float2 xv = *(const float2*)(x + (size_t)(b0 + s * 64 + m) * 50 + (t + 1) * 2);
#pragma unroll
                for (int c = 0; c < 9; ++c) {
                    ushort4 pk;
                    pk.x = bfu(yv[c].x); pk.y = bfu(yv[c].y);
                    pk.z = bfu(yv[c].z); pk.w = bfu(yv[c].w);
                    int k0 = 4 * c;
                    int l2v = (m & 15) | (((k0 >> 2) & 3) << 4);
                    int j0 = ((k0 >> 4) & 1) << 2;
                    ushort* dst = (ushort*)(base + O_AY) +
                                  (((ws * 8 + mt * 2 + (k0 >> 5)) << 9) + (l2v << 3) + j0);
                    *(ushort4*)dst = pk;
                }
                union { uint u; ushort sh[2]; } xu;
                xu.sh[0] = bfu(xv.x); xu.sh[1] = bfu(xv.y);
                *(uint*)((ushort*)(base + O_A1) + (((ws * 4 + mt) << 9) + ((m & 15) << 3))) = xu.u;
            }
        }
        __syncthreads();

        // ---- P2: FC2 (w0-4) | FC3+FC4 for t-1 (w5-8) ----
        if (wave < 5) {
#pragma unroll
            for (int s = 0; s < 2; ++s) {
                bf16* base = sb + s * SSTR;
#pragma unroll
                for (int mt = 0; mt < 4; ++mt) {
                    f32x4 acc = {0.f, 0.f, 0.f, 0.f};
#pragma unroll
                    for (int kc = 0; kc < 2; ++kc) {
                        bf16x8 a = *(const bf16x8*)(base + O_AT1 + ((mt * 2 + kc) << 9) + (lane << 3));
                        acc = MFMA(a, bF2[kc], acc, 0, 0, 0);
                    }
                    int n = (wave << 4) + ln15;
                    if (n < 72) {
                        int mrow = (mt << 4) + ((lane >> 4) << 2);
#pragma unroll
                        for (int r = 0; r < 4; ++r)
                            st_frag(base + O_A2, 9, mrow + r, n, acc[r] + biasF2);
                    }
                }
            }
        } else if (t > 0) { // h3(t-1) is in AH3 slot rs
            const int mt = wave - 5;
#pragma unroll
            for (int s = 0; s < 2; ++s) {
                bf16* base = sb + s * SSTR;
                bf16x8 a = *(const bf16x8*)(base + O_AH3 + ((rs * 4 + mt) << 9) + (lane << 3));
                f32x4 acc = {0.f, 0.f, 0.f, 0.f};
                acc = MFMA(a, bF3, acc, 0, 0, 0);
#pragma unroll
                for (int r = 0; r < 4; ++r) {
                    float u = fmaxf(acc[r] + biasF3, 0.0f);
                    float s0 = u * w40, s1 = u * w41;
                    s0 += qperm<0xB1>(s0);  s1 += qperm<0xB1>(s1);
                    s0 += qperm<0x4E>(s0);  s1 += qperm<0x4E>(s1);
                    s0 += qperm<0x124>(s0); s1 += qperm<0x124>(s1);
                    s0 += qperm<0x128>(s0); s1 += qperm<0x128>(s1);
                    if (ln15 == 0) {
                        int mrow = (mt << 4) + ((lane >> 4) << 2) + r;
                        float2 o; o.x = s0 + b40; o.y = s1 + b41;
                        *(float2*)(out + (size_t)(b0 + s * 64 + mrow) * 50 + (t - 1) * 2) = o;
                    }
                }
            }
        }
        __syncthreads();

        // ---- P3: LSTM2 (all 9 waves), fused EW ----
#pragma unroll
        for (int mt = 0; mt < 4; ++mt) {
#pragma unroll
            for (int s = 0; s < 2; ++s) {
                bf16* base = sb + s * SSTR;
                bf16x8 al[6];
#pragma unroll
                for (int j = 0; j < 3; ++j)
                    al[j] = *(const bf16x8*)(base + O_A2 + ((mt * 9 + j) << 9) + (lane << 3));
#pragma unroll
                for (int j = 0; j < 3; ++j)
                    al[3 + j] = *(const bf16x8*)(base + O_A2 + ((mt * 9 + 3 + 3 * rs + j) << 9) + (lane << 3));
#pragma unroll
                for (int ntl = 0; ntl < 2; ++ntl) {
                    const int nt = wave + ntl * 9;
                    f32x4 acc = {0.f, 0.f, 0.f, 0.f};
#pragma unroll
                    for (int b = 0; b < 6; ++b) acc = MFMA(al[b], bL2[ntl][b], acc, 0, 0, 0);
                    lstm_tile_ew(acc, biasL2[ntl], c2[s][ntl][mt], lane, [&](float hv) {
                        int m = (mt << 4) + ((lane >> 4) << 2) + (lane & 3);
                        int h = (nt << 2) + ((lane >> 2) & 3);
                        st_frag(base + O_A2, 9, m, (3 + 3 * ws) * 32 + h, hv);
                    });
                }
            }
        }
        __syncthreads();

        // ---- P4: LSTM3 (w0-7): A1[ws](h1 new) + A2 h2[ws](new) + AH3[rs](h3 old) ----
        if (wave < 8) {
#pragma unroll
            for (int s = 0; s < 2; ++s) {
                bf16* base = sb + s * SSTR;
#pragma unroll
                for (int mt = 0; mt < 4; ++mt) {
                    f32x4 acc = {0.f, 0.f, 0.f, 0.f};
                    bf16x8 a0 = *(const bf16x8*)(base + O_A1 + ((ws * 4 + mt) << 9) + (lane << 3));
                    acc = MFMA(a0, bL3[0], acc, 0, 0, 0);
#pragma unroll
                    for (int j = 0; j < 3; ++j) {
                        bf16x8 a = *(const bf16x8*)(base + O_A2 + ((mt * 9 + 3 + 3 * ws + j) << 9) + (lane << 3));
                        acc = MFMA(a, bL3[1 + j], acc, 0, 0, 0);
                    }
                    bf16x8 a4 = *(const bf16x8*)(base + O_AH3 + ((rs * 4 + mt) << 9) + (lane << 3));
                    acc = MFMA(a4, bL3[4], acc, 0, 0, 0);
                    lstm_tile_ew(acc, biasL3, c3[s][mt], lane, [&](float hv) {
                        int m = (mt << 4) + ((lane >> 4) << 2) + (lane & 3);
                        int h = (wave << 2) + ((lane >> 2) & 3);
                        st_frag(base + O_AH3 + ((ws * 4) << 9), 1, m, h, hv);
                    });
                }
            }
        }
        __syncthreads();
    }

    // ---- epilogue: FC3+FC4 for t=24; h3(24) is in AH3 slot 1 ----
    if (wave >= 5) {
        const int mt = wave - 5;
#pragma unroll
        for (int s = 0; s < 2; ++s) {
            bf16* base = sb + s * SSTR;
            bf16x8 a = *(const bf16x8*)(base + O_AH3 + ((4 + mt) << 9) + (lane << 3));
            f32x4 acc = {0.f, 0.f, 0.f, 0.f};
            acc = MFMA(a, bF3, acc, 0, 0, 0);
#pragma unroll
            for (int r = 0; r < 4; ++r) {
                float u = fmaxf(acc[r] + biasF3, 0.0f);
                float s0 = u * w40, s1 = u * w41;
                s0 += qperm<0xB1>(s0);  s1 += qperm<0xB1>(s1);
                s0 += qperm<0x4E>(s0);  s1 += qperm<0x4E>(s1);
                s0 += qperm<0x124>(s0); s1 += qperm<0x124>(s1);
                s0 += qperm<0x128>(s0); s1 += qperm<0x128>(s1);
                if (ln15 == 0) {
                    int mrow = (mt << 4) + ((lane >> 4) << 2) + r;
                    float2 o; o.x = s0 + b40; o.y = s1 + b41;
                    *(float2*)(out + (size_t)(b0 + s * 64 + mrow) * 50 + 24 * 2) = o;
                }
            }
        }
    }
}

extern "C" void kernel_launch(void* const* d_in, const int* in_sizes, int n_in,
                              void* d_out, int out_size, void* d_ws, size_t ws_size,
                              hipStream_t stream) {
    (void)in_sizes; (void)n_in; (void)d_ws; (void)ws_size; (void)out_size;
    hipFuncSetAttribute((const void*)lstm_fused,
                        hipFuncAttributeMaxDynamicSharedMemorySize, LDS_BYTES);
    lstm_fused<<<dim3(1024), dim3(THREADS), LDS_BYTES, stream>>>(
        (const float*)d_in[0], (const float*)d_in[1],
        (const float*)d_in[2], (const float*)d_in[3],
        (const float*)d_in[4], (const float*)d_in[5],
        (const float*)d_in[6], (const float*)d_in[7],
        (const float*)d_in[8], (const float*)d_in[9],
        (const float*)d_in[10], (const float*)d_in[11],
        (const float*)d_in[12], (const float*)d_in[13],
        (const float*)d_in[14], (const float*)d_in[15],
        (const float*)d_in[16], (const float*)d_in[17],
        (const float*)d_in[18], (const float*)d_in[19],
        (const float*)d_in[20], (const float*)d_in[21],
        (float*)d_out);
}

// Round 6
// 1383.413 us; speedup vs baseline: 1.3231x; 1.3231x over previous
//
#include <hip/hip_runtime.h>
#include <hip/hip_bf16.h>

#define THREADS 768

typedef __hip_bfloat16 bf16;
typedef __attribute__((ext_vector_type(4))) float f32x4;
typedef __attribute__((ext_vector_type(8))) short bf16x8;

#define MFMA __builtin_amdgcn_mfma_f32_16x16x32_bf16

// ---- LDS layout (bf16 elems), blocks of 512 = one 16x32 fragment tile
#define O_A1  0       // 2 slots x 4mt : [x(2)|h1(16)|pad14]
#define O_AY  4096    // 2 slots x 4mt x 2kc : [y(36)|pad]
#define O_AT1 12288   // 4mt x 2kc : t1(64)
#define O_A2  16384   // 4mt x 8 chunks: [c0,c1,c2,c3,c4, c2',c3',c4']  K=[l2(72)|h2(72)|pad16]
#define O_AH3 32768   // 2 slots x 4mt : h3(32)
#define LDS_ELEMS 36864
#define LDS_BYTES (LDS_ELEMS * 2)   // 73728

// self-consistent K mapping within a 16x32 fragment tile (verified round 1)
__device__ __forceinline__ int kmap(int l, int j) {
    return (((l >> 4) & 3) << 2) + (j & 3) + ((j >> 2) << 4);
}
__device__ __forceinline__ int frag_off(int m, int k) { // k in [0,32)
    int l = (m & 15) | (((k >> 2) & 3) << 4);
    int j = (k & 3) | (((k >> 4) & 1) << 2);
    return (l << 3) + j;
}
__device__ __forceinline__ void st_frag(bf16* sbase, int KC, int m, int k, float v) {
    sbase[(((m >> 4) * KC + (k >> 5)) << 9) + frag_off(m, k & 31)] = __float2bfloat16(v);
}
__device__ __forceinline__ void st_frag_c(bf16* sbase, int KC, int m, int cidx, int kl, float v) {
    sbase[(((m >> 4) * KC + cidx) << 9) + frag_off(m, kl)] = __float2bfloat16(v);
}

__device__ __forceinline__ float rcp_(float x) { return __builtin_amdgcn_rcpf(x); }
__device__ __forceinline__ float sigm(float x) { return rcp_(1.0f + __expf(-x)); }
__device__ __forceinline__ float tanh_(float x) { return 1.0f - 2.0f * rcp_(1.0f + __expf(2.0f * x)); }

__device__ __forceinline__ float pick4(float a, float b, float c, float d, int j) {
    float ab = (j & 1) ? b : a;
    float cd = (j & 1) ? d : c;
    return (j & 2) ? cd : ab;
}

// DPP lane permute (VALU). quad xor1=0xB1, xor2=0x4E, xor3=0x1B; row_ror4=0x124, ror8=0x128
template <int CTRL>
__device__ __forceinline__ float qperm(float v) {
    return __int_as_float(__builtin_amdgcn_mov_dpp(__float_as_int(v), CTRL, 0xF, 0xF, true));
}

__device__ __forceinline__ ushort bfu(float f) {
    union { bf16 b; ushort u; } v; v.b = __float2bfloat16(f); return v.u;
}

// fused gate-EW for interleaved-gate tiles: col n = h*4+g ; lane (g=lane&3) does row base+g
template <typename WR>
__device__ __forceinline__ void lstm_tile_ew(f32x4 acc, float bias, float& cst, int lane, WR wr) {
    int g = lane & 3;
    float a0 = acc[0] + bias, a1 = acc[1] + bias, a2 = acc[2] + bias, a3 = acc[3] + bias;
    float own = pick4(a0, a1, a2, a3, g);
    float p1 = pick4(a0, a1, a2, a3, g ^ 1);
    float p2 = pick4(a0, a1, a2, a3, g ^ 2);
    float p3 = pick4(a0, a1, a2, a3, g ^ 3);
    float q1 = qperm<0xB1>(p1);
    float q2 = qperm<0x4E>(p2);
    float q3 = qperm<0x1B>(p3);
    float iv = pick4(own, q1, q2, q3, g);
    float fv = pick4(own, q1, q2, q3, g ^ 1);
    float gv = pick4(own, q1, q2, q3, g ^ 2);
    float ov = pick4(own, q1, q2, q3, g ^ 3);
    float c = sigm(fv) * cst + sigm(iv) * tanh_(gv);
    cst = c;
    wr(sigm(ov) * tanh_(c));
}

template <typename F>
__device__ __forceinline__ bf16x8 mk_frag(int lane, F val) { // val(k), k in [0,32)
    union { bf16x8 v; bf16 h[8]; } u;
#pragma unroll
    for (int j = 0; j < 8; ++j) u.h[j] = __float2bfloat16(val(kmap(lane, j)));
    return u.v;
}

__global__ void __launch_bounds__(THREADS, 3)
lstm_fused(const float* __restrict__ x, const float* __restrict__ y,
           const float* __restrict__ Wih1, const float* __restrict__ Whh1,
           const float* __restrict__ bih1, const float* __restrict__ bhh1,
           const float* __restrict__ Wih2, const float* __restrict__ Whh2,
           const float* __restrict__ bih2, const float* __restrict__ bhh2,
           const float* __restrict__ Wih3, const float* __restrict__ Whh3,
           const float* __restrict__ bih3, const float* __restrict__ bhh3,
           const float* __restrict__ W1, const float* __restrict__ b1,
           const float* __restrict__ W2, const float* __restrict__ b2,
           const float* __restrict__ W3, const float* __restrict__ b3,
           const float* __restrict__ W4, const float* __restrict__ b4,
           float* __restrict__ out) {
    extern __shared__ char smem[];
    bf16* sb = (bf16*)smem;
    const int tid = threadIdx.x;
    const int wave = tid >> 6, lane = tid & 63, ln15 = lane & 15;
    const int b0 = blockIdx.x * 64;

    // ---- per-wave register-resident B fragments + biases ----
    // w0-3: LSTM1(nt=w) + LSTM2-heavy(2nt) + FC3/4          (~48 B-regs)
    // w4-5: LSTM2-heavy + LSTM3(nt=w-4)                     (~60)
    // w6:   LSTM2-light + FC2(nt=4) + LSTM3                 (~48)
    // w7:   LSTM2-light + LSTM3                             (~40)
    // w8-11: LSTM2-light + FC1(nt=w-8) + FC2(nt=w-8) + LSTM3 (~56)
    bf16x8 bL1 = {};  float biasL1 = 0.f;
    bf16x8 bF1[2] = {}; float biasF1 = 0.f;
    bf16x8 bF2[2] = {}; float biasF2 = 0.f;
    bf16x8 bL2[2][5]; float biasL2[2] = {0.f, 0.f};
    bf16x8 bL3[5] = {}; float biasL3 = 0.f;
    bf16x8 bF3 = {};  float biasF3 = 0.f, w40 = 0.f, w41 = 0.f, b40 = 0.f, b41 = 0.f;

    if (wave < 4) { // LSTM1 gates interleaved: nt=wave, H=16
        int n = (wave << 4) + ln15;
        int r = (n & 3) * 16 + (n >> 2);
        biasL1 = bih1[r] + bhh1[r];
        bL1 = mk_frag(lane, [&](int k) {
            return k < 2 ? Wih1[r * 2 + k] : (k < 18 ? Whh1[r * 16 + (k - 2)] : 0.0f); });
        // FC3 (mt=wave) + FC4 scalars
        int n3 = ln15;
        biasF3 = b3[n3]; w40 = W4[n3]; w41 = W4[16 + n3];
        b40 = b4[0]; b41 = b4[1];
        bF3 = mk_frag(lane, [&](int k) { return W3[n3 * 32 + k]; });
    }
    if (wave >= 8) { // FC1: nt=wave-8
        int n = ((wave - 8) << 4) + ln15;
        biasF1 = b1[n];
#pragma unroll
        for (int kc = 0; kc < 2; ++kc)
            bF1[kc] = mk_frag(lane, [&](int kl) {
                int k = kc * 32 + kl; return k < 36 ? W1[n * 36 + k] : 0.0f; });
    }
    { // FC2 owners: w8-11 (nt=w-8) + w6 (nt=4)
        int ntF2 = (wave == 6) ? 4 : (wave >= 8 ? wave - 8 : -1);
        if (ntF2 >= 0) {
            int n = (ntF2 << 4) + ln15;
            biasF2 = (n < 72) ? b2[n] : 0.0f;
#pragma unroll
            for (int kc = 0; kc < 2; ++kc)
                bF2[kc] = mk_frag(lane, [&](int kl) {
                    int k = kc * 32 + kl; return (n < 72) ? W2[n * 64 + k] : 0.0f; });
        }
    }
    { // LSTM2 interleaved, K repacked to 5 chunks: [l2(72)|h2(72)|pad16]
        auto fillL2 = [&](int nt, bf16x8* dst, float& bias) {
            int n = (nt << 4) + ln15;
            int r = (n & 3) * 72 + (n >> 2);
            bias = bih2[r] + bhh2[r];
#pragma unroll
            for (int kc = 0; kc < 5; ++kc)
                dst[kc] = mk_frag(lane, [&](int kl) {
                    int k = kc * 32 + kl;
                    return k < 72 ? Wih2[r * 72 + k]
                                  : (k < 144 ? Whh2[r * 72 + (k - 72)] : 0.0f); });
        };
        int nt0 = (wave < 6) ? wave * 2 : wave + 6;
        fillL2(nt0, bL2[0], biasL2[0]);
        if (wave < 6) fillL2(wave * 2 + 1, bL2[1], biasL2[1]);
    }
    if (wave >= 4) { // LSTM3 interleaved: nt=wave-4, H=32
        int n = ((wave - 4) << 4) + ln15;
        int r = (n & 3) * 32 + (n >> 2);
        biasL3 = bih3[r] + bhh3[r];
        // A-chunks: A1-tile[x2|h1 16|pad] ; A2 c2 (l2tail8|h2 0..23) ; A2 c3 (h2 24..55);
        //           A2 c4 (h2 56..71|pad) ; AH3 (h3)
        bL3[0] = mk_frag(lane, [&](int k) {
            return (k >= 2 && k < 18) ? Wih3[r * 88 + (k - 2)] : 0.0f; });
        bL3[1] = mk_frag(lane, [&](int k) {
            return (k >= 8) ? Wih3[r * 88 + 8 + k] : 0.0f; });
        bL3[2] = mk_frag(lane, [&](int k) { return Wih3[r * 88 + 40 + k]; });
        bL3[3] = mk_frag(lane, [&](int k) {
            return (k < 16) ? Wih3[r * 88 + 72 + k] : 0.0f; });
        bL3[4] = mk_frag(lane, [&](int k) { return Whh3[r * 32 + k]; });
    }

    // ---- zero LDS ----
    {
        int4* z = (int4*)sb;
        int4 zv = {0, 0, 0, 0};
        for (int i = tid; i < LDS_BYTES / 16; i += THREADS) z[i] = zv;
    }
    __syncthreads();
    // ---- stage x(0), y(0) into slot 0 ----
    if (tid < 128) {
        int m = tid >> 1, k = tid & 1;
        st_frag(sb + O_A1, 1, m, k, x[(size_t)(b0 + m) * 50 + k]);
    }
    for (int it = tid; it < 64 * 36; it += THREADS) {
        int m = it / 36, k = it - m * 36;
        st_frag(sb + O_AY, 2, m, k, y[(size_t)(b0 + m) * 900 + k]);
    }
    float c1[4] = {};
    float c2[2][4] = {};
    float c3[4] = {};
    __syncthreads();

    for (int t = 0; t < 25; ++t) {
        const int rs = t & 1, ws = rs ^ 1;

        // ---- P1: LSTM1 (w0-3) | stage y/x(t+1) (w4-7) | FC1 (w8-11) ----
        if (wave < 4) {
#pragma unroll
            for (int mt = 0; mt < 4; ++mt) {
                bf16x8 a = *(const bf16x8*)(sb + O_A1 + ((rs * 4 + mt) << 9) + (lane << 3));
                f32x4 acc = {0.f, 0.f, 0.f, 0.f};
                acc = MFMA(a, bL1, acc, 0, 0, 0);
                lstm_tile_ew(acc, biasL1, c1[mt], lane, [&](float hv) {
                    int m = (mt << 4) + ((lane >> 4) << 2) + (lane & 3);
                    int h = (wave << 2) + ((lane >> 2) & 3);
                    st_frag(sb + O_A1 + ((ws * 4) << 9), 1, m, 2 + h, hv);
                });
            }
        } else if (wave < 8) {
            if (t < 24) {
                const int sidx = wave - 4;
                const int m = lane, mt = m >> 4;
                const float* yp = y + (size_t)(b0 + m) * 900 + (t + 1) * 36;
#pragma unroll
                for (int c = sidx; c < 9; c += 4) {
                    float4 v = *(const float4*)(yp + 4 * c);
                    ushort4 pk;
                    pk.x = bfu(v.x); pk.y = bfu(v.y); pk.z = bfu(v.z); pk.w = bfu(v.w);
                    int k0 = 4 * c, kc = k0 >> 5;
                    int l2v = (m & 15) | (((k0 >> 2) & 3) << 4);
                    int j0 = ((k0 >> 4) & 1) << 2;
                    *(ushort4*)((ushort*)(sb + O_AY) +
                                (((ws * 8 + mt * 2 + kc)) << 9) + (l2v << 3) + j0) = pk;
                }
                if (wave == 5) {
                    float2 xv = *(const float2*)(x + (size_t)(b0 + m) * 50 + (t + 1) * 2);
                    union { uint u; ushort s[2]; } xu;
                    xu.s[0] = bfu(xv.x); xu.s[1] = bfu(xv.y);
                    *(uint*)((ushort*)(sb + O_A1) + ((ws * 4 + mt) << 9) + ((m & 15) << 3)) = xu.u;
                }
            }
        } else {
            const int nt = wave - 8;
#pragma unroll
            for (int mt = 0; mt < 4; ++mt) {
                f32x4 acc = {0.f, 0.f, 0.f, 0.f};
#pragma unroll
                for (int kc = 0; kc < 2; ++kc) {
                    bf16x8 a = *(const bf16x8*)(sb + O_AY + ((rs * 8 + mt * 2 + kc) << 9) + (lane << 3));
                    acc = MFMA(a, bF1[kc], acc, 0, 0, 0);
                }
                int n = (nt << 4) + ln15;
                int mrow = (mt << 4) + ((lane >> 4) << 2);
#pragma unroll
                for (int r = 0; r < 4; ++r)
                    st_frag(sb + O_AT1, 2, mrow + r, n, fmaxf(acc[r] + biasF1, 0.0f));
            }
        }
        __syncthreads();

        // ---- P2: FC3+FC4(t-1) (w0-3) | FC2 (w6, w8-11) ----
        if (wave < 4) {
            if (t > 0) { // h3(t-1) in AH3 slot rs
                const int mt = wave;
                bf16x8 a = *(const bf16x8*)(sb + O_AH3 + ((rs * 4 + mt) << 9) + (lane << 3));
                f32x4 acc = {0.f, 0.f, 0.f, 0.f};
                acc = MFMA(a, bF3, acc, 0, 0, 0);
#pragma unroll
                for (int r = 0; r < 4; ++r) {
                    float u = fmaxf(acc[r] + biasF3, 0.0f);
                    float s0 = u * w40, s1 = u * w41;
                    s0 += qperm<0xB1>(s0);  s1 += qperm<0xB1>(s1);
                    s0 += qperm<0x4E>(s0);  s1 += qperm<0x4E>(s1);
                    s0 += qperm<0x124>(s0); s1 += qperm<0x124>(s1);
                    s0 += qperm<0x128>(s0); s1 += qperm<0x128>(s1);
                    if (ln15 == 0) {
                        int mrow = (mt << 4) + ((lane >> 4) << 2) + r;
                        float2 o; o.x = s0 + b40; o.y = s1 + b41;
                        *(float2*)(out + (size_t)(b0 + mrow) * 50 + (t - 1) * 2) = o;
                    }
                }
            }
        } else {
            const int ntF2 = (wave == 6) ? 4 : (wave >= 8 ? wave - 8 : -1);
            if (ntF2 >= 0) {
#pragma unroll
                for (int mt = 0; mt < 4; ++mt) {
                    f32x4 acc = {0.f, 0.f, 0.f, 0.f};
#pragma unroll
                    for (int kc = 0; kc < 2; ++kc) {
                        bf16x8 a = *(const bf16x8*)(sb + O_AT1 + ((mt * 2 + kc) << 9) + (lane << 3));
                        acc = MFMA(a, bF2[kc], acc, 0, 0, 0);
                    }
                    int n = (ntF2 << 4) + ln15;
                    if (n < 72) {
                        int mrow = (mt << 4) + ((lane >> 4) << 2);
                        int cidx = n >> 5, kl = n & 31;
#pragma unroll
                        for (int r = 0; r < 4; ++r) {
                            float v = acc[r] + biasF2;
                            st_frag_c(sb + O_A2, 8, mrow + r, cidx, kl, v);
                            if (cidx == 2)  // l2 tail lives in both h2 buffer copies
                                st_frag_c(sb + O_A2, 8, mrow + r, 5, kl, v);
                        }
                    }
                }
            }
        }
        __syncthreads();

        // ---- P3: LSTM2 (all 12 waves; w0-5 heavy 2nt, w6-11 light 1nt) ----
        {
            const int nt0 = (wave < 6) ? wave * 2 : wave + 6;
#pragma unroll
            for (int mt = 0; mt < 4; ++mt) {
                bf16x8 al[5];
                al[0] = *(const bf16x8*)(sb + O_A2 + ((mt * 8 + 0) << 9) + (lane << 3));
                al[1] = *(const bf16x8*)(sb + O_A2 + ((mt * 8 + 1) << 9) + (lane << 3));
#pragma unroll
                for (int j = 0; j < 3; ++j)
                    al[2 + j] = *(const bf16x8*)(sb + O_A2 + ((mt * 8 + 2 + j + 3 * rs) << 9) + (lane << 3));
                {
                    f32x4 acc = {0.f, 0.f, 0.f, 0.f};
#pragma unroll
                    for (int b = 0; b < 5; ++b) acc = MFMA(al[b], bL2[0][b], acc, 0, 0, 0);
                    lstm_tile_ew(acc, biasL2[0], c2[0][mt], lane, [&](float hv) {
                        int m = (mt << 4) + ((lane >> 4) << 2) + (lane & 3);
                        int kg = 72 + (nt0 << 2) + ((lane >> 2) & 3);
                        st_frag_c(sb + O_A2, 8, m, (kg >> 5) + 3 * ws, kg & 31, hv);
                    });
                }
                if (wave < 6) {
                    f32x4 acc = {0.f, 0.f, 0.f, 0.f};
#pragma unroll
                    for (int b = 0; b < 5; ++b) acc = MFMA(al[b], bL2[1][b], acc, 0, 0, 0);
                    lstm_tile_ew(acc, biasL2[1], c2[1][mt], lane, [&](float hv) {
                        int m = (mt << 4) + ((lane >> 4) << 2) + (lane & 3);
                        int kg = 72 + ((nt0 + 1) << 2) + ((lane >> 2) & 3);
                        st_frag_c(sb + O_A2, 8, m, (kg >> 5) + 3 * ws, kg & 31, hv);
                    });
                }
            }
        }
        __syncthreads();

        // ---- P4: LSTM3 (w4-11): A1[ws](x+h1 new) + A2 h2[ws](new) + AH3[rs](h3 old) ----
        if (wave >= 4) {
            const int nt = wave - 4;
#pragma unroll
            for (int mt = 0; mt < 4; ++mt) {
                f32x4 acc = {0.f, 0.f, 0.f, 0.f};
                bf16x8 a0 = *(const bf16x8*)(sb + O_A1 + ((ws * 4 + mt) << 9) + (lane << 3));
                acc = MFMA(a0, bL3[0], acc, 0, 0, 0);
#pragma unroll
                for (int j = 0; j < 3; ++j) {
                    bf16x8 a = *(const bf16x8*)(sb + O_A2 + ((mt * 8 + 2 + j + 3 * ws) << 9) + (lane << 3));
                    acc = MFMA(a, bL3[1 + j], acc, 0, 0, 0);
                }
                bf16x8 a4 = *(const bf16x8*)(sb + O_AH3 + ((rs * 4 + mt) << 9) + (lane << 3));
                acc = MFMA(a4, bL3[4], acc, 0, 0, 0);
                lstm_tile_ew(acc, biasL3, c3[mt], lane, [&](float hv) {
                    int m = (mt << 4) + ((lane >> 4) << 2) + (lane & 3);
                    int h = (nt << 2) + ((lane >> 2) & 3);
                    st_frag(sb + O_AH3 + ((ws * 4) << 9), 1, m, h, hv);
                });
            }
        }
        __syncthreads();
    }

    // ---- epilogue: FC3+FC4 for t=24; h3(24) in AH3 slot 1 ----
    if (wave < 4) {
        const int mt = wave;
        bf16x8 a = *(const bf16x8*)(sb + O_AH3 + ((4 + mt) << 9) + (lane << 3));
        f32x4 acc = {0.f, 0.f, 0.f, 0.f};
        acc = MFMA(a, bF3, acc, 0, 0, 0);
#pragma unroll
        for (int r = 0; r < 4; ++r) {
            float u = fmaxf(acc[r] + biasF3, 0.0f);
            float s0 = u * w40, s1 = u * w41;
            s0 += qperm<0xB1>(s0);  s1 += qperm<0xB1>(s1);
            s0 += qperm<0x4E>(s0);  s1 += qperm<0x4E>(s1);
            s0 += qperm<0x124>(s0); s1 += qperm<0x124>(s1);
            s0 += qperm<0x128>(s0); s1 += qperm<0x128>(s1);
            if (ln15 == 0) {
                int mrow = (mt << 4) + ((lane >> 4) << 2) + r;
                float2 o; o.x = s0 + b40; o.y = s1 + b41;
                *(float2*)(out + (size_t)(b0 + mrow) * 50 + 24 * 2) = o;
            }
        }
    }
}

extern "C" void kernel_launch(void* const* d_in, const int* in_sizes, int n_in,
                              void* d_out, int out_size, void* d_ws, size_t ws_size,
                              hipStream_t stream) {
    (void)in_sizes; (void)n_in; (void)d_ws; (void)ws_size; (void)out_size;
    hipFuncSetAttribute((const void*)lstm_fused,
                        hipFuncAttributeMaxDynamicSharedMemorySize, LDS_BYTES);
    lstm_fused<<<dim3(2048), dim3(THREADS), LDS_BYTES, stream>>>(
        (const float*)d_in[0], (const float*)d_in[1],
        (const float*)d_in[2], (const float*)d_in[3],
        (const float*)d_in[4], (const float*)d_in[5],
        (const float*)d_in[6], (const float*)d_in[7],
        (const float*)d_in[8], (const float*)d_in[9],
        (const float*)d_in[10], (const float*)d_in[11],
        (const float*)d_in[12], (const float*)d_in[13],
        (const float*)d_in[14], (const float*)d_in[15],
        (const float*)d_in[16], (const float*)d_in[17],
        (const float*)d_in[18], (const float*)d_in[19],
        (const float*)d_in[20], (const float*)d_in[21],
        (float*)d_out);
}

// Round 7
// 1258.318 us; speedup vs baseline: 1.4547x; 1.0994x over previous
//
#include <hip/hip_runtime.h>
#include <hip/hip_bf16.h>

#define THREADS 768

typedef __hip_bfloat16 bf16;
typedef __attribute__((ext_vector_type(4))) float f32x4;
typedef __attribute__((ext_vector_type(8))) short bf16x8;

#define MFMA __builtin_amdgcn_mfma_f32_16x16x32_bf16

// ---- LDS layout (bf16 elems), blocks of 512 = one 16x32 fragment tile
#define O_A1  0       // 2 slots x 4mt : [x(2)|h1(16)|pad14]
#define O_AY  4096    // 2 slots x 4mt x 2kc : [y(36)|pad]
#define O_AT1 12288   // 4mt x 2kc : t1(64), single-buffered
#define O_A2  16384   // 4mt x 10 chunks: [c0s0,c0s1,c1s0,c1s1,c2s0,c2s1,c3s0,c3s1,c4s0,c4s1]
                      // K = [l2(72)|h2(72)|pad16]; c2 = l2-tail(kl<8)+h2-head(kl>=8)
#define O_AH3 36864   // 2 slots x 4mt : h3(32)
#define LDS_ELEMS 40960
#define LDS_BYTES (LDS_ELEMS * 2)   // 81920

// self-consistent K mapping within a 16x32 fragment tile (verified round 1)
__device__ __forceinline__ int kmap(int l, int j) {
    return (((l >> 4) & 3) << 2) + (j & 3) + ((j >> 2) << 4);
}
__device__ __forceinline__ int frag_off(int m, int k) { // k in [0,32)
    int l = (m & 15) | (((k >> 2) & 3) << 4);
    int j = (k & 3) | (((k >> 4) & 1) << 2);
    return (l << 3) + j;
}
__device__ __forceinline__ void st_frag(bf16* sbase, int KC, int m, int k, float v) {
    sbase[(((m >> 4) * KC + (k >> 5)) << 9) + frag_off(m, k & 31)] = __float2bfloat16(v);
}
__device__ __forceinline__ void st_frag_c(bf16* sbase, int KC, int m, int cidx, int kl, float v) {
    sbase[(((m >> 4) * KC + cidx) << 9) + frag_off(m, kl)] = __float2bfloat16(v);
}

__device__ __forceinline__ float rcp_(float x) { return __builtin_amdgcn_rcpf(x); }
__device__ __forceinline__ float sigm(float x) { return rcp_(1.0f + __expf(-x)); }
__device__ __forceinline__ float tanh_(float x) { return 1.0f - 2.0f * rcp_(1.0f + __expf(2.0f * x)); }

__device__ __forceinline__ float pick4(float a, float b, float c, float d, int j) {
    float ab = (j & 1) ? b : a;
    float cd = (j & 1) ? d : c;
    return (j & 2) ? cd : ab;
}

// DPP lane permute (VALU). quad xor1=0xB1, xor2=0x4E, xor3=0x1B; row_ror4=0x124, ror8=0x128
template <int CTRL>
__device__ __forceinline__ float qperm(float v) {
    return __int_as_float(__builtin_amdgcn_mov_dpp(__float_as_int(v), CTRL, 0xF, 0xF, true));
}

__device__ __forceinline__ ushort bfu(float f) {
    union { bf16 b; ushort u; } v; v.b = __float2bfloat16(f); return v.u;
}

// fused gate-EW for interleaved-gate tiles: col n = h*4+g ; lane (g=lane&3) does row base+g
template <typename WR>
__device__ __forceinline__ void lstm_tile_ew(f32x4 acc, float bias, float& cst, int lane, WR wr) {
    int g = lane & 3;
    float a0 = acc[0] + bias, a1 = acc[1] + bias, a2 = acc[2] + bias, a3 = acc[3] + bias;
    float own = pick4(a0, a1, a2, a3, g);
    float p1 = pick4(a0, a1, a2, a3, g ^ 1);
    float p2 = pick4(a0, a1, a2, a3, g ^ 2);
    float p3 = pick4(a0, a1, a2, a3, g ^ 3);
    float q1 = qperm<0xB1>(p1);
    float q2 = qperm<0x4E>(p2);
    float q3 = qperm<0x1B>(p3);
    float iv = pick4(own, q1, q2, q3, g);
    float fv = pick4(own, q1, q2, q3, g ^ 1);
    float gv = pick4(own, q1, q2, q3, g ^ 2);
    float ov = pick4(own, q1, q2, q3, g ^ 3);
    float c = sigm(fv) * cst + sigm(iv) * tanh_(gv);
    cst = c;
    wr(sigm(ov) * tanh_(c));
}

template <typename F>
__device__ __forceinline__ bf16x8 mk_frag(int lane, F val) { // val(k), k in [0,32)
    union { bf16x8 v; bf16 h[8]; } u;
#pragma unroll
    for (int j = 0; j < 8; ++j) u.h[j] = __float2bfloat16(val(kmap(lane, j)));
    return u.v;
}

__global__ void __launch_bounds__(THREADS, 3)
lstm_fused(const float* __restrict__ x, const float* __restrict__ y,
           const float* __restrict__ Wih1, const float* __restrict__ Whh1,
           const float* __restrict__ bih1, const float* __restrict__ bhh1,
           const float* __restrict__ Wih2, const float* __restrict__ Whh2,
           const float* __restrict__ bih2, const float* __restrict__ bhh2,
           const float* __restrict__ Wih3, const float* __restrict__ Whh3,
           const float* __restrict__ bih3, const float* __restrict__ bhh3,
           const float* __restrict__ W1, const float* __restrict__ b1,
           const float* __restrict__ W2, const float* __restrict__ b2,
           const float* __restrict__ W3, const float* __restrict__ b3,
           const float* __restrict__ W4, const float* __restrict__ b4,
           float* __restrict__ out) {
    extern __shared__ char smem[];
    bf16* sb = (bf16*)smem;
    const int tid = threadIdx.x;
    const int wave = tid >> 6, lane = tid & 63, ln15 = lane & 15;
    const int b0 = blockIdx.x * 64;

    // ---- wave roles ----
    // w0-3 : PA heavy-LSTM2(nt 2w,2w+1)        | PB FC2(nt=w + nt4@mt=w) + FC3/4(mt=w)
    // w4-7 : PA LSTM1+FC1(nt=w-4), light L2    | PB LSTM3(nt=w-4)        (w4: x-stage)
    // w8-9 : PA heavy-LSTM2(nt 2w-8,2w-7)      | PB LSTM3
    // w10-11: PA light-LSTM2(nt=w+6) + y-stage | PB LSTM3
    const bool HEAVY = (wave < 4) || wave == 8 || wave == 9;
    const int ntA = wave < 4 ? 2 * wave : (wave < 8 ? wave + 8 : (wave < 10 ? 2 * wave - 8 : wave + 6));
    const int ntB = wave < 4 ? 2 * wave + 1 : 2 * wave - 7;

    bf16x8 bL1 = {};  float biasL1 = 0.f;
    bf16x8 bF1[2] = {}; float biasF1 = 0.f;
    bf16x8 bF2[2] = {}, bF2s[2] = {}; float biasF2 = 0.f, biasF2s = 0.f;
    bf16x8 bL2[2][5]; float biasL2[2] = {0.f, 0.f};
    bf16x8 bL3[5] = {}; float biasL3 = 0.f;
    bf16x8 bF3 = {};  float biasF3 = 0.f, w40 = 0.f, w41 = 0.f, b40 = 0.f, b41 = 0.f;

    { // LSTM2 interleaved, K = [l2(72)|h2(72)|pad16], 5 chunks
        auto fillL2 = [&](int nt, bf16x8* dst, float& bias) {
            int n = (nt << 4) + ln15;
            int r = (n & 3) * 72 + (n >> 2);
            bias = bih2[r] + bhh2[r];
#pragma unroll
            for (int kc = 0; kc < 5; ++kc)
                dst[kc] = mk_frag(lane, [&](int kl) {
                    int k = kc * 32 + kl;
                    return k < 72 ? Wih2[r * 72 + k]
                                  : (k < 144 ? Whh2[r * 72 + (k - 72)] : 0.0f); });
        };
        fillL2(ntA, bL2[0], biasL2[0]);
        if (HEAVY) fillL2(ntB, bL2[1], biasL2[1]);
        else { bL2[1][0] = bL2[0][0]; bL2[1][1] = bL2[0][0]; bL2[1][2] = bL2[0][0];
               bL2[1][3] = bL2[0][0]; bL2[1][4] = bL2[0][0]; }
    }
    if (wave >= 4 && wave < 8) { // LSTM1 + FC1, nt = wave-4
        int n = ((wave - 4) << 4) + ln15;
        int r = (n & 3) * 16 + (n >> 2);
        biasL1 = bih1[r] + bhh1[r];
        bL1 = mk_frag(lane, [&](int k) {
            return k < 2 ? Wih1[r * 2 + k] : (k < 18 ? Whh1[r * 16 + (k - 2)] : 0.0f); });
        biasF1 = b1[n];
#pragma unroll
        for (int kc = 0; kc < 2; ++kc)
            bF1[kc] = mk_frag(lane, [&](int kl) {
                int k = kc * 32 + kl; return k < 36 ? W1[n * 36 + k] : 0.0f; });
    }
    if (wave >= 4) { // LSTM3 interleaved: nt = wave-4, H=32
        int n = ((wave - 4) << 4) + ln15;
        int r = (n & 3) * 32 + (n >> 2);
        biasL3 = bih3[r] + bhh3[r];
        bL3[0] = mk_frag(lane, [&](int k) {
            return (k >= 2 && k < 18) ? Wih3[r * 88 + (k - 2)] : 0.0f; });
        bL3[1] = mk_frag(lane, [&](int k) {
            return (k >= 8) ? Wih3[r * 88 + 8 + k] : 0.0f; });
        bL3[2] = mk_frag(lane, [&](int k) { return Wih3[r * 88 + 40 + k]; });
        bL3[3] = mk_frag(lane, [&](int k) {
            return (k < 16) ? Wih3[r * 88 + 72 + k] : 0.0f; });
        bL3[4] = mk_frag(lane, [&](int k) { return Whh3[r * 32 + k]; });
    }
    if (wave < 4) { // FC2 (own nt=wave + shared nt4) + FC3/FC4
        int n = (wave << 4) + ln15;   // < 64
        biasF2 = b2[n];
#pragma unroll
        for (int kc = 0; kc < 2; ++kc)
            bF2[kc] = mk_frag(lane, [&](int kl) { return W2[n * 64 + kc * 32 + kl]; });
        int ns = 64 + ln15;
        biasF2s = (ns < 72) ? b2[ns] : 0.0f;
#pragma unroll
        for (int kc = 0; kc < 2; ++kc)
            bF2s[kc] = mk_frag(lane, [&](int kl) {
                return (ns < 72) ? W2[ns * 64 + kc * 32 + kl] : 0.0f; });
        biasF3 = b3[ln15]; w40 = W4[ln15]; w41 = W4[16 + ln15];
        b40 = b4[0]; b41 = b4[1];
        bF3 = mk_frag(lane, [&](int k) { return W3[ln15 * 32 + k]; });
    }

    // ---- zero LDS ----
    {
        int4* z = (int4*)sb;
        int4 zv = {0, 0, 0, 0};
        for (int i = tid; i < LDS_BYTES / 16; i += THREADS) z[i] = zv;
    }
    __syncthreads();
    // ---- prologue: stage y0->AY[0], y1->AY[1], x0->A1[0] ----
    for (int it = tid; it < 2 * 2304; it += THREADS) {
        int slot = it / 2304, r2 = it - slot * 2304;
        int m = r2 / 36, k = r2 - m * 36;
        st_frag(sb + O_AY + ((slot * 8) << 9), 2, m, k,
                y[(size_t)(b0 + m) * 900 + slot * 36 + k]);
    }
    if (tid < 128) {
        int m = tid >> 1, k = tid & 1;
        st_frag(sb + O_A1, 1, m, k, x[(size_t)(b0 + m) * 50 + k]);
    }
    __syncthreads();
    // ---- prologue FC1(0) on w4-7 ----
    if (wave >= 4 && wave < 8) {
#pragma unroll
        for (int mt = 0; mt < 4; ++mt) {
            f32x4 acc = {0.f, 0.f, 0.f, 0.f};
#pragma unroll
            for (int kc = 0; kc < 2; ++kc) {
                bf16x8 a = *(const bf16x8*)(sb + O_AY + ((mt * 2 + kc) << 9) + (lane << 3));
                acc = MFMA(a, bF1[kc], acc, 0, 0, 0);
            }
            int n = ((wave - 4) << 4) + ln15;
            int mrow = (mt << 4) + ((lane >> 4) << 2);
#pragma unroll
            for (int r = 0; r < 4; ++r)
                st_frag(sb + O_AT1, 2, mrow + r, n, fmaxf(acc[r] + biasF1, 0.0f));
        }
    }
    __syncthreads();
    // ---- prologue FC2(0) on w0-3 -> l2 slot 0 ----
    if (wave < 4) {
#pragma unroll
        for (int mt = 0; mt < 4; ++mt) {
            f32x4 acc = {0.f, 0.f, 0.f, 0.f};
#pragma unroll
            for (int kc = 0; kc < 2; ++kc) {
                bf16x8 a = *(const bf16x8*)(sb + O_AT1 + ((mt * 2 + kc) << 9) + (lane << 3));
                acc = MFMA(a, bF2[kc], acc, 0, 0, 0);
            }
            int n = (wave << 4) + ln15;
            int mrow = (mt << 4) + ((lane >> 4) << 2);
#pragma unroll
            for (int r = 0; r < 4; ++r)
                st_frag_c(sb + O_A2, 10, mrow + r, ((n >> 5) << 1), n & 31, acc[r] + biasF2);
        }
        {
            const int mt = wave;
            f32x4 acc = {0.f, 0.f, 0.f, 0.f};
#pragma unroll
            for (int kc = 0; kc < 2; ++kc) {
                bf16x8 a = *(const bf16x8*)(sb + O_AT1 + ((mt * 2 + kc) << 9) + (lane << 3));
                acc = MFMA(a, bF2s[kc], acc, 0, 0, 0);
            }
            if (ln15 < 8) {
                int n = 64 + ln15;
                int mrow = (mt << 4) + ((lane >> 4) << 2);
#pragma unroll
                for (int r = 0; r < 4; ++r)
                    st_frag_c(sb + O_A2, 10, mrow + r, 4, n & 31, acc[r] + biasF2s);
            }
        }
    }
    float c1[4] = {};
    float cs2[2][4] = {};
    float c3[4] = {};
    __syncthreads();

    for (int t = 0; t < 25; ++t) {
        const int rs = t & 1, ws = rs ^ 1;

        // ======== PA: LSTM2(all) | LSTM1+FC1(t+1)(w4-7) | y(t+2)(w10-11) | x(t+1)(w4) ========
        if (wave >= 4 && wave < 8) {
            const int nt1 = wave - 4;
#pragma unroll
            for (int mt = 0; mt < 4; ++mt) { // LSTM1
                bf16x8 a = *(const bf16x8*)(sb + O_A1 + ((rs * 4 + mt) << 9) + (lane << 3));
                f32x4 acc = {0.f, 0.f, 0.f, 0.f};
                acc = MFMA(a, bL1, acc, 0, 0, 0);
                lstm_tile_ew(acc, biasL1, c1[mt], lane, [&](float hv) {
                    int m = (mt << 4) + ((lane >> 4) << 2) + (lane & 3);
                    int h = (nt1 << 2) + ((lane >> 2) & 3);
                    st_frag(sb + O_A1 + ((ws * 4) << 9), 1, m, 2 + h, hv);
                });
            }
            if (t < 24) { // FC1(t+1) from AY[ws]
#pragma unroll
                for (int mt = 0; mt < 4; ++mt) {
                    f32x4 acc = {0.f, 0.f, 0.f, 0.f};
#pragma unroll
                    for (int kc = 0; kc < 2; ++kc) {
                        bf16x8 a = *(const bf16x8*)(sb + O_AY + ((ws * 8 + mt * 2 + kc) << 9) + (lane << 3));
                        acc = MFMA(a, bF1[kc], acc, 0, 0, 0);
                    }
                    int n = ((wave - 4) << 4) + ln15;
                    int mrow = (mt << 4) + ((lane >> 4) << 2);
#pragma unroll
                    for (int r = 0; r < 4; ++r)
                        st_frag(sb + O_AT1, 2, mrow + r, n, fmaxf(acc[r] + biasF1, 0.0f));
                }
            }
            if (wave == 4 && t < 24) { // x(t+1) -> A1[ws]
                const int m = lane, mt = m >> 4;
                float2 xv = *(const float2*)(x + (size_t)(b0 + m) * 50 + (t + 1) * 2);
                union { uint u; ushort s[2]; } xu;
                xu.s[0] = bfu(xv.x); xu.s[1] = bfu(xv.y);
                *(uint*)((ushort*)(sb + O_A1) + ((ws * 4 + mt) << 9) + ((m & 15) << 3)) = xu.u;
            }
        } else if (wave >= 10 && t < 23) { // y(t+2) -> AY[rs]
            const int m = ((wave - 10) << 5) + (lane >> 1);
            const int mt = m >> 4;
            const float* yp = y + (size_t)(b0 + m) * 900 + (t + 2) * 36;
#pragma unroll
            for (int c = (lane & 1); c < 9; c += 2) {
                float4 v = *(const float4*)(yp + 4 * c);
                ushort4 pk;
                pk.x = bfu(v.x); pk.y = bfu(v.y); pk.z = bfu(v.z); pk.w = bfu(v.w);
                int k0 = 4 * c, kc = k0 >> 5;
                int l2v = (m & 15) | (((k0 >> 2) & 3) << 4);
                int j0 = ((k0 >> 4) & 1) << 2;
                *(ushort4*)((ushort*)(sb + O_AY) + ((rs * 8 + mt * 2 + kc) << 9) + (l2v << 3) + j0) = pk;
            }
        }
        // LSTM2 on all waves
#pragma unroll
        for (int mt = 0; mt < 4; ++mt) {
            bf16x8 al[5];
#pragma unroll
            for (int b = 0; b < 5; ++b)
                al[b] = *(const bf16x8*)(sb + O_A2 + ((mt * 10 + 2 * b + rs) << 9) + (lane << 3));
            {
                f32x4 acc = {0.f, 0.f, 0.f, 0.f};
#pragma unroll
                for (int b = 0; b < 5; ++b) acc = MFMA(al[b], bL2[0][b], acc, 0, 0, 0);
                lstm_tile_ew(acc, biasL2[0], cs2[0][mt], lane, [&](float hv) {
                    int m = (mt << 4) + ((lane >> 4) << 2) + (lane & 3);
                    int kg = 72 + (ntA << 2) + ((lane >> 2) & 3);
                    st_frag_c(sb + O_A2, 10, m, ((kg >> 5) << 1) + ws, kg & 31, hv);
                });
            }
            if (HEAVY) {
                f32x4 acc = {0.f, 0.f, 0.f, 0.f};
#pragma unroll
                for (int b = 0; b < 5; ++b) acc = MFMA(al[b], bL2[1][b], acc, 0, 0, 0);
                lstm_tile_ew(acc, biasL2[1], cs2[1][mt], lane, [&](float hv) {
                    int m = (mt << 4) + ((lane >> 4) << 2) + (lane & 3);
                    int kg = 72 + (ntB << 2) + ((lane >> 2) & 3);
                    st_frag_c(sb + O_A2, 10, m, ((kg >> 5) << 1) + ws, kg & 31, hv);
                });
            }
        }
        __syncthreads();

        // ======== PB: LSTM3(w4-11) | FC2(t+1)+FC3/4(t-1)(w0-3) ========
        if (wave >= 4) {
            const int nt = wave - 4;
#pragma unroll
            for (int mt = 0; mt < 4; ++mt) {
                f32x4 acc = {0.f, 0.f, 0.f, 0.f};
                bf16x8 a0 = *(const bf16x8*)(sb + O_A1 + ((ws * 4 + mt) << 9) + (lane << 3));
                acc = MFMA(a0, bL3[0], acc, 0, 0, 0);
#pragma unroll
                for (int j = 0; j < 3; ++j) {
                    bf16x8 a = *(const bf16x8*)(sb + O_A2 + ((mt * 10 + 4 + 2 * j + ws) << 9) + (lane << 3));
                    acc = MFMA(a, bL3[1 + j], acc, 0, 0, 0);
                }
                bf16x8 a4 = *(const bf16x8*)(sb + O_AH3 + ((rs * 4 + mt) << 9) + (lane << 3));
                acc = MFMA(a4, bL3[4], acc, 0, 0, 0);
                lstm_tile_ew(acc, biasL3, c3[mt], lane, [&](float hv) {
                    int m = (mt << 4) + ((lane >> 4) << 2) + (lane & 3);
                    int h = (nt << 2) + ((lane >> 2) & 3);
                    st_frag(sb + O_AH3 + ((ws * 4) << 9), 1, m, h, hv);
                });
            }
        } else {
            if (t < 24) { // FC2(t+1) -> l2 slot ws
#pragma unroll
                for (int mt = 0; mt < 4; ++mt) {
                    f32x4 acc = {0.f, 0.f, 0.f, 0.f};
#pragma unroll
                    for (int kc = 0; kc < 2; ++kc) {
                        bf16x8 a = *(const bf16x8*)(sb + O_AT1 + ((mt * 2 + kc) << 9) + (lane << 3));
                        acc = MFMA(a, bF2[kc], acc, 0, 0, 0);
                    }
                    int n = (wave << 4) + ln15;
                    int mrow = (mt << 4) + ((lane >> 4) << 2);
#pragma unroll
                    for (int r = 0; r < 4; ++r)
                        st_frag_c(sb + O_A2, 10, mrow + r, ((n >> 5) << 1) + ws, n & 31, acc[r] + biasF2);
                }
                {
                    const int mt = wave;
                    f32x4 acc = {0.f, 0.f, 0.f, 0.f};
#pragma unroll
                    for (int kc = 0; kc < 2; ++kc) {
                        bf16x8 a = *(const bf16x8*)(sb + O_AT1 + ((mt * 2 + kc) << 9) + (lane << 3));
                        acc = MFMA(a, bF2s[kc], acc, 0, 0, 0);
                    }
                    if (ln15 < 8) {
                        int n = 64 + ln15;
                        int mrow = (mt << 4) + ((lane >> 4) << 2);
#pragma unroll
                        for (int r = 0; r < 4; ++r)
                            st_frag_c(sb + O_A2, 10, mrow + r, 4 + ws, n & 31, acc[r] + biasF2s);
                    }
                }
            }
            if (t > 0) { // FC3+FC4 for t-1, h3(t-1) in AH3[rs]
                const int mt = wave;
                bf16x8 a = *(const bf16x8*)(sb + O_AH3 + ((rs * 4 + mt) << 9) + (lane << 3));
                f32x4 acc = {0.f, 0.f, 0.f, 0.f};
                acc = MFMA(a, bF3, acc, 0, 0, 0);
#pragma unroll
                for (int r = 0; r < 4; ++r) {
                    float u = fmaxf(acc[r] + biasF3, 0.0f);
                    float s0 = u * w40, s1 = u * w41;
                    s0 += qperm<0xB1>(s0);  s1 += qperm<0xB1>(s1);
                    s0 += qperm<0x4E>(s0);  s1 += qperm<0x4E>(s1);
                    s0 += qperm<0x124>(s0); s1 += qperm<0x124>(s1);
                    s0 += qperm<0x128>(s0); s1 += qperm<0x128>(s1);
                    if (ln15 == 0) {
                        int mrow = (mt << 4) + ((lane >> 4) << 2) + r;
                        float2 o; o.x = s0 + b40; o.y = s1 + b41;
                        *(float2*)(out + (size_t)(b0 + mrow) * 50 + (t - 1) * 2) = o;
                    }
                }
            }
        }
        __syncthreads();
    }

    // ---- epilogue: FC3+FC4 for t=24; h3(24) in AH3 slot 1 ----
    if (wave < 4) {
        const int mt = wave;
        bf16x8 a = *(const bf16x8*)(sb + O_AH3 + ((4 + mt) << 9) + (lane << 3));
        f32x4 acc = {0.f, 0.f, 0.f, 0.f};
        acc = MFMA(a, bF3, acc, 0, 0, 0);
#pragma unroll
        for (int r = 0; r < 4; ++r) {
            float u = fmaxf(acc[r] + biasF3, 0.0f);
            float s0 = u * w40, s1 = u * w41;
            s0 += qperm<0xB1>(s0);  s1 += qperm<0xB1>(s1);
            s0 += qperm<0x4E>(s0);  s1 += qperm<0x4E>(s1);
            s0 += qperm<0x124>(s0); s1 += qperm<0x124>(s1);
            s0 += qperm<0x128>(s0); s1 += qperm<0x128>(s1);
            if (ln15 == 0) {
                int mrow = (mt << 4) + ((lane >> 4) << 2) + r;
                float2 o; o.x = s0 + b40; o.y = s1 + b41;
                *(float2*)(out + (size_t)(b0 + mrow) * 50 + 24 * 2) = o;
            }
        }
    }
}

extern "C" void kernel_launch(void* const* d_in, const int* in_sizes, int n_in,
                              void* d_out, int out_size, void* d_ws, size_t ws_size,
                              hipStream_t stream) {
    (void)in_sizes; (void)n_in; (void)d_ws; (void)ws_size; (void)out_size;
    hipFuncSetAttribute((const void*)lstm_fused,
                        hipFuncAttributeMaxDynamicSharedMemorySize, LDS_BYTES);
    lstm_fused<<<dim3(2048), dim3(THREADS), LDS_BYTES, stream>>>(
        (const float*)d_in[0], (const float*)d_in[1],
        (const float*)d_in[2], (const float*)d_in[3],
        (const float*)d_in[4], (const float*)d_in[5],
        (const float*)d_in[6], (const float*)d_in[7],
        (const float*)d_in[8], (const float*)d_in[9],
        (const float*)d_in[10], (const float*)d_in[11],
        (const float*)d_in[12], (const float*)d_in[13],
        (const float*)d_in[14], (const float*)d_in[15],
        (const float*)d_in[16], (const float*)d_in[17],
        (const float*)d_in[18], (const float*)d_in[19],
        (const float*)d_in[20], (const float*)d_in[21],
        (float*)d_out);
}

// Round 8
// 1247.351 us; speedup vs baseline: 1.4675x; 1.0088x over previous
//
#include <hip/hip_runtime.h>
#include <hip/hip_bf16.h>

#define THREADS 768

typedef __hip_bfloat16 bf16;
typedef __attribute__((ext_vector_type(4))) float f32x4;
typedef __attribute__((ext_vector_type(8))) short bf16x8;

#define MFMA __builtin_amdgcn_mfma_f32_16x16x32_bf16

// ---- LDS layout (bf16 elems), blocks of 512 = one fragment tile (N=16 batch x K=32)
#define O_A1  0       // 2 slots x 4mt : K=[x(2)|h1(16)|k18=1|pad]
#define O_AY  4096    // 2 slots x 4mt x 2kc : K=[y(36)... k36=1|pad]
#define O_AT1 12288   // 4mt x 2kc : t1(64), single-buffered
#define O_A2  16384   // 4mt x 10 chunks [c0s0,c0s1,...,c4s0,c4s1], K=[l2(72)|h2(72)|k144=1|pad]
#define O_AH3 36864   // 2 slots x 4mt : h3(32)
#define LDS_ELEMS 40960
#define LDS_BYTES (LDS_ELEMS * 2)   // 81920

// self-consistent K mapping within a fragment tile (verified rounds 1-7)
__device__ __forceinline__ int kmap(int l, int j) {
    return (((l >> 4) & 3) << 2) + (j & 3) + ((j >> 2) << 4);
}
__device__ __forceinline__ int frag_off(int m, int k) { // k in [0,32)
    int l = (m & 15) | (((k >> 2) & 3) << 4);
    int j = (k & 3) | (((k >> 4) & 1) << 2);
    return (l << 3) + j;
}
__device__ __forceinline__ void st_frag(bf16* sbase, int KC, int m, int k, float v) {
    sbase[(((m >> 4) * KC + (k >> 5)) << 9) + frag_off(m, k & 31)] = __float2bfloat16(v);
}
__device__ __forceinline__ void st_frag_c(bf16* sbase, int KC, int m, int cidx, int kl, float v) {
    sbase[(((m >> 4) * KC + cidx) << 9) + frag_off(m, kl)] = __float2bfloat16(v);
}

__device__ __forceinline__ float rcp_(float x) { return __builtin_amdgcn_rcpf(x); }

// swapped-operand gate EW: lane's acc = {i,f,g,o} preacts (bias MFMA-folded). 4 exp + 3 rcp.
__device__ __forceinline__ float lstm_ew1(f32x4 acc, float& cst) {
    float ei = __expf(-acc[0]);
    float ef = __expf(-acc[1]);
    float eg = __expf(2.0f * fminf(acc[2], 40.0f));
    float eo = __expf(-acc[3]);
    float c = rcp_(1.0f + ef) * cst + (eg - 1.0f) * rcp_((1.0f + ei) * (eg + 1.0f));
    cst = c;
    float ec = __expf(2.0f * fminf(c, 40.0f));
    return (ec - 1.0f) * rcp_((1.0f + eo) * (ec + 1.0f));
}

__device__ __forceinline__ ushort bfu(float f) {
    union { bf16 b; ushort u; } v; v.b = __float2bfloat16(f); return v.u;
}

template <typename F>
__device__ __forceinline__ bf16x8 mk_frag(int lane, F val) { // val(k), k in [0,32)
    union { bf16x8 v; bf16 h[8]; } u;
#pragma unroll
    for (int j = 0; j < 8; ++j) u.h[j] = __float2bfloat16(val(kmap(lane, j)));
    return u.v;
}

__global__ void __launch_bounds__(THREADS, 3)
lstm_fused(const float* __restrict__ x, const float* __restrict__ y,
           const float* __restrict__ Wih1, const float* __restrict__ Whh1,
           const float* __restrict__ bih1, const float* __restrict__ bhh1,
           const float* __restrict__ Wih2, const float* __restrict__ Whh2,
           const float* __restrict__ bih2, const float* __restrict__ bhh2,
           const float* __restrict__ Wih3, const float* __restrict__ Whh3,
           const float* __restrict__ bih3, const float* __restrict__ bhh3,
           const float* __restrict__ W1, const float* __restrict__ b1,
           const float* __restrict__ W2, const float* __restrict__ b2,
           const float* __restrict__ W3, const float* __restrict__ b3,
           const float* __restrict__ W4, const float* __restrict__ b4,
           float* __restrict__ out) {
    extern __shared__ char smem[];
    bf16* sb = (bf16*)smem;
    const int tid = threadIdx.x;
    const int wave = tid >> 6, lane = tid & 63, ln15 = lane & 15;
    const int b0 = blockIdx.x * 64;

    // ---- wave roles (weights = A operand: M rows = gates h*4+g / features) ----
    // PA: w0-5 heavy L2 (nt 2w,2w+1); w6-9 L1(nt w-6) + light L2 (nt 12+w-6), w6 x-stage;
    //     w10-11 y-stage + FC1 (nt 2(w-10),+1) + light L2 (nt 16+w-10)
    // PB: w0-3 FC2 (w0: nt0+nt4; w1-3: nt w) + FC3/4(mt=w); w4-11 L3 (nt w-4)
    const bool HEAVY = wave < 6;
    const int ntL2a = HEAVY ? 2 * wave : 6 + wave;

    bf16x8 bL2[2][5];
    bf16x8 bL1 = {};
    bf16x8 bF1[2][2] = {};
    bf16x8 bF2[2][2] = {};
    bf16x8 bL3[5] = {};
    bf16x8 bF3 = {};

    { // LSTM2: K=[l2 72|h2 72|bias@144|pad]
        auto fillL2 = [&](int nt, bf16x8* dst) {
            int R = (nt << 4) + ln15;
            int r = (R & 3) * 72 + (R >> 2);
            float bias = bih2[r] + bhh2[r];
#pragma unroll
            for (int kc = 0; kc < 5; ++kc)
                dst[kc] = mk_frag(lane, [&](int kl) {
                    int k = kc * 32 + kl;
                    return k < 72 ? Wih2[r * 72 + k]
                         : (k < 144 ? Whh2[r * 72 + (k - 72)]
                         : (k == 144 ? bias : 0.0f)); });
        };
        fillL2(ntL2a, bL2[0]);
        if (HEAVY) fillL2(2 * wave + 1, bL2[1]);
        else { bL2[1][0] = bL2[0][0]; bL2[1][1] = bL2[0][0]; bL2[1][2] = bL2[0][0];
               bL2[1][3] = bL2[0][0]; bL2[1][4] = bL2[0][0]; }
    }
    if (wave >= 6 && wave < 10) { // LSTM1: K=[x 2|h1 16|bias@18|pad]
        int R = ((wave - 6) << 4) + ln15;
        int r = (R & 3) * 16 + (R >> 2);
        float bias = bih1[r] + bhh1[r];
        bL1 = mk_frag(lane, [&](int k) {
            return k < 2 ? Wih1[r * 2 + k]
                 : (k < 18 ? Whh1[r * 16 + (k - 2)]
                 : (k == 18 ? bias : 0.0f)); });
    }
    if (wave >= 10) { // FC1: K=[y 36|bias@36... wait bias at k=36]
#pragma unroll
        for (int nn = 0; nn < 2; ++nn) {
            int n = ((2 * (wave - 10) + nn) << 4) + ln15;
            float bias = b1[n];
#pragma unroll
            for (int kc = 0; kc < 2; ++kc)
                bF1[nn][kc] = mk_frag(lane, [&](int kl) {
                    int k = kc * 32 + kl;
                    return k < 36 ? W1[n * 36 + k] : (k == 36 ? bias : 0.0f); });
        }
    }
    if (wave >= 4) { // LSTM3: chunks A1[x|h1|bias@18] ; A2 c2,c3,c4 (h2) ; AH3 h3
        int R = ((wave - 4) << 4) + ln15;
        int r = (R & 3) * 32 + (R >> 2);
        float bias = bih3[r] + bhh3[r];
        bL3[0] = mk_frag(lane, [&](int k) {
            return (k >= 2 && k < 18) ? Wih3[r * 88 + (k - 2)] : (k == 18 ? bias : 0.0f); });
        bL3[1] = mk_frag(lane, [&](int k) {
            return (k >= 8) ? Wih3[r * 88 + 8 + k] : 0.0f; });
        bL3[2] = mk_frag(lane, [&](int k) { return Wih3[r * 88 + 40 + k]; });
        bL3[3] = mk_frag(lane, [&](int k) {
            return (k < 16) ? Wih3[r * 88 + 72 + k] : 0.0f; });
        bL3[4] = mk_frag(lane, [&](int k) { return Whh3[r * 32 + k]; });
    }
    if (wave < 4) { // FC2 (reg-bias, loaded per step) + FC3
#pragma unroll
        for (int nn = 0; nn < 2; ++nn) {
            int nt2 = (nn == 0) ? ((wave == 0) ? 0 : wave) : 4;
            bool use = (nn == 0) || (wave == 0);
            int n = (nt2 << 4) + ln15;
#pragma unroll
            for (int kc = 0; kc < 2; ++kc)
                bF2[nn][kc] = mk_frag(lane, [&](int kl) {
                    return (use && n < 72) ? W2[n * 64 + kc * 32 + kl] : 0.0f; });
        }
        bF3 = mk_frag(lane, [&](int k) { return W3[ln15 * 32 + k]; });
    }

    // ---- zero LDS ----
    {
        int4* z = (int4*)sb;
        int4 zv = {0, 0, 0, 0};
        for (int i = tid; i < LDS_BYTES / 16; i += THREADS) z[i] = zv;
    }
    __syncthreads();
    // ---- stage y0->AY[0], y1->AY[1], x0->A1[0], and const-1 bias lanes ----
    for (int it = tid; it < 2 * 2304; it += THREADS) {
        int slot = it / 2304, r2 = it - slot * 2304;
        int m = r2 / 36, k = r2 - m * 36;
        st_frag(sb + O_AY + ((slot * 8) << 9), 2, m, k,
                y[(size_t)(b0 + m) * 900 + slot * 36 + k]);
    }
    if (tid < 128) {
        int m = tid >> 1, k = tid & 1;
        st_frag(sb + O_A1, 1, m, k, x[(size_t)(b0 + m) * 50 + k]);
    }
    {
        const bf16 one = __float2bfloat16(1.0f);
        if (tid < 128) { // A1 k=18, both slots
            int s = tid >> 6, mt = (tid >> 4) & 3, n = tid & 15;
            sb[O_A1 + ((s * 4 + mt) << 9) + frag_off(n, 18)] = one;
        } else if (tid < 256) { // AY k=36 (chunk1, kl=4), both slots
            int i = tid - 128; int s = i >> 6, mt = (i >> 4) & 3, n = i & 15;
            sb[O_AY + ((s * 8 + mt * 2 + 1) << 9) + frag_off(n, 4)] = one;
        } else if (tid < 384) { // A2 k=144 (chunk c4, kl=16), both slots
            int i = tid - 256; int s = i >> 6, mt = (i >> 4) & 3, n = i & 15;
            sb[O_A2 + ((mt * 10 + 8 + s) << 9) + frag_off(n, 16)] = one;
        }
    }
    __syncthreads();
    // ---- prologue FC1(0) on w10-11 (reads AY slot0) ----
    if (wave >= 10) {
#pragma unroll
        for (int nn = 0; nn < 2; ++nn) {
            int nf = ((2 * (wave - 10) + nn) << 4) + ((lane >> 4) << 2);
#pragma unroll
            for (int mt = 0; mt < 4; ++mt) {
                f32x4 acc = {0.f, 0.f, 0.f, 0.f};
#pragma unroll
                for (int kc = 0; kc < 2; ++kc) {
                    bf16x8 a = *(const bf16x8*)(sb + O_AY + ((mt * 2 + kc) << 9) + (lane << 3));
                    acc = MFMA(bF1[nn][kc], a, acc, 0, 0, 0);
                }
                int batch = (mt << 4) + ln15;
#pragma unroll
                for (int r = 0; r < 4; ++r)
                    st_frag(sb + O_AT1, 2, batch, nf + r, fmaxf(acc[r], 0.0f));
            }
        }
    }
    __syncthreads();
    // ---- prologue FC2(0) on w0-3 -> l2 slot0 ----
    if (wave < 4) {
        const int nN = (wave == 0) ? 2 : 1;
        for (int nn = 0; nn < nN; ++nn) {
            int nt2 = (wave == 0) ? (nn ? 4 : 0) : wave;
            int nb = (nt2 << 4) + ((lane >> 4) << 2);
            float4 bv = {0.f, 0.f, 0.f, 0.f};
            if (nb < 72) bv = *(const float4*)(b2 + nb);
#pragma unroll
            for (int mt = 0; mt < 4; ++mt) {
                f32x4 acc = {0.f, 0.f, 0.f, 0.f};
#pragma unroll
                for (int kc = 0; kc < 2; ++kc) {
                    bf16x8 a = *(const bf16x8*)(sb + O_AT1 + ((mt * 2 + kc) << 9) + (lane << 3));
                    acc = MFMA(bF2[nn][kc], a, acc, 0, 0, 0);
                }
                if (nb < 72) {
                    int batch = (mt << 4) + ln15;
#pragma unroll
                    for (int r = 0; r < 4; ++r) {
                        int n = nb + r;
                        st_frag_c(sb + O_A2, 10, batch, ((n >> 5) << 1), n & 31, acc[r] + bv[r]);
                    }
                }
            }
        }
    }
    float c1[4] = {};
    float cs2[2][4] = {};
    float c3[4] = {};
    __syncthreads();

    for (int t = 0; t < 25; ++t) {
        const int rs = t & 1, ws = rs ^ 1;

        // ======== PA ========
        if (!HEAVY) {
            if (wave < 10) { // LSTM1 (nt1 = wave-6) + x-stage(w6)
                const int nt1 = wave - 6;
#pragma unroll
                for (int mt = 0; mt < 4; ++mt) {
                    bf16x8 a = *(const bf16x8*)(sb + O_A1 + ((rs * 4 + mt) << 9) + (lane << 3));
                    f32x4 acc = {0.f, 0.f, 0.f, 0.f};
                    acc = MFMA(bL1, a, acc, 0, 0, 0);
                    float hv = lstm_ew1(acc, c1[mt]);
                    int batch = (mt << 4) + ln15;
                    st_frag(sb + O_A1 + ((ws * 4) << 9), 1, batch,
                            2 + (nt1 << 2) + (lane >> 4), hv);
                }
                if (wave == 6 && t < 24) {
                    const int m = lane, mt = m >> 4;
                    float2 xv = *(const float2*)(x + (size_t)(b0 + m) * 50 + (t + 1) * 2);
                    union { uint u; ushort s[2]; } xu;
                    xu.s[0] = bfu(xv.x); xu.s[1] = bfu(xv.y);
                    *(uint*)((ushort*)(sb + O_A1) + ((ws * 4 + mt) << 9) + ((m & 15) << 3)) = xu.u;
                }
            } else { // w10-11: y(t+2) stage + FC1(t+1)
                if (t < 23) {
                    const int m = ((wave - 10) << 5) + (lane >> 1);
                    const int mt = m >> 4;
                    const float* yp = y + (size_t)(b0 + m) * 900 + (t + 2) * 36;
#pragma unroll
                    for (int c = (lane & 1); c < 9; c += 2) {
                        float4 v = *(const float4*)(yp + 4 * c);
                        ushort4 pk;
                        pk.x = bfu(v.x); pk.y = bfu(v.y); pk.z = bfu(v.z); pk.w = bfu(v.w);
                        int k0 = 4 * c, kc = k0 >> 5;
                        int l2v = (m & 15) | (((k0 >> 2) & 3) << 4);
                        int j0 = ((k0 >> 4) & 1) << 2;
                        *(ushort4*)((ushort*)(sb + O_AY) +
                                    ((rs * 8 + mt * 2 + kc) << 9) + (l2v << 3) + j0) = pk;
                    }
                }
                if (t < 24) {
#pragma unroll
                    for (int nn = 0; nn < 2; ++nn) {
                        int nf = ((2 * (wave - 10) + nn) << 4) + ((lane >> 4) << 2);
#pragma unroll
                        for (int mt = 0; mt < 4; ++mt) {
                            f32x4 acc = {0.f, 0.f, 0.f, 0.f};
#pragma unroll
                            for (int kc = 0; kc < 2; ++kc) {
                                bf16x8 a = *(const bf16x8*)(sb + O_AY + ((ws * 8 + mt * 2 + kc) << 9) + (lane << 3));
                                acc = MFMA(bF1[nn][kc], a, acc, 0, 0, 0);
                            }
                            int batch = (mt << 4) + ln15;
#pragma unroll
                            for (int r = 0; r < 4; ++r)
                                st_frag(sb + O_AT1, 2, batch, nf + r, fmaxf(acc[r], 0.0f));
                        }
                    }
                }
            }
        }
        // LSTM2 on all waves
#pragma unroll
        for (int mt = 0; mt < 4; ++mt) {
            bf16x8 al[5];
#pragma unroll
            for (int b = 0; b < 5; ++b)
                al[b] = *(const bf16x8*)(sb + O_A2 + ((mt * 10 + 2 * b + rs) << 9) + (lane << 3));
            {
                f32x4 acc = {0.f, 0.f, 0.f, 0.f};
#pragma unroll
                for (int b = 0; b < 5; ++b) acc = MFMA(bL2[0][b], al[b], acc, 0, 0, 0);
                float hv = lstm_ew1(acc, cs2[0][mt]);
                int batch = (mt << 4) + ln15;
                int k = 72 + (ntL2a << 2) + (lane >> 4);
                st_frag_c(sb + O_A2, 10, batch, ((k >> 5) << 1) + ws, k & 31, hv);
            }
            if (HEAVY) {
                f32x4 acc = {0.f, 0.f, 0.f, 0.f};
#pragma unroll
                for (int b = 0; b < 5; ++b) acc = MFMA(bL2[1][b], al[b], acc, 0, 0, 0);
                float hv = lstm_ew1(acc, cs2[1][mt]);
                int batch = (mt << 4) + ln15;
                int k = 72 + ((2 * wave + 1) << 2) + (lane >> 4);
                st_frag_c(sb + O_A2, 10, batch, ((k >> 5) << 1) + ws, k & 31, hv);
            }
        }
        __syncthreads();

        // ======== PB ========
        if (wave >= 4) { // LSTM3
            const int nt3 = wave - 4;
#pragma unroll
            for (int mt = 0; mt < 4; ++mt) {
                f32x4 acc = {0.f, 0.f, 0.f, 0.f};
                bf16x8 a0 = *(const bf16x8*)(sb + O_A1 + ((ws * 4 + mt) << 9) + (lane << 3));
                acc = MFMA(bL3[0], a0, acc, 0, 0, 0);
#pragma unroll
                for (int j = 0; j < 3; ++j) {
                    bf16x8 a = *(const bf16x8*)(sb + O_A2 + ((mt * 10 + 4 + 2 * j + ws) << 9) + (lane << 3));
                    acc = MFMA(bL3[1 + j], a, acc, 0, 0, 0);
                }
                bf16x8 a4 = *(const bf16x8*)(sb + O_AH3 + ((rs * 4 + mt) << 9) + (lane << 3));
                acc = MFMA(bL3[4], a4, acc, 0, 0, 0);
                float hv = lstm_ew1(acc, c3[mt]);
                int batch = (mt << 4) + ln15;
                st_frag(sb + O_AH3 + ((ws * 4) << 9), 1, batch, (nt3 << 2) + (lane >> 4), hv);
            }
        } else {
            if (t < 24) { // FC2(t+1) -> l2 slot ws
                const int nN = (wave == 0) ? 2 : 1;
                for (int nn = 0; nn < nN; ++nn) {
                    int nt2 = (wave == 0) ? (nn ? 4 : 0) : wave;
                    int nb = (nt2 << 4) + ((lane >> 4) << 2);
                    float4 bv = {0.f, 0.f, 0.f, 0.f};
                    if (nb < 72) bv = *(const float4*)(b2 + nb);
#pragma unroll
                    for (int mt = 0; mt < 4; ++mt) {
                        f32x4 acc = {0.f, 0.f, 0.f, 0.f};
#pragma unroll
                        for (int kc = 0; kc < 2; ++kc) {
                            bf16x8 a = *(const bf16x8*)(sb + O_AT1 + ((mt * 2 + kc) << 9) + (lane << 3));
                            acc = MFMA(bF2[nn][kc], a, acc, 0, 0, 0);
                        }
                        if (nb < 72) {
                            int batch = (mt << 4) + ln15;
#pragma unroll
                            for (int r = 0; r < 4; ++r) {
                                int n = nb + r;
                                st_frag_c(sb + O_A2, 10, batch, ((n >> 5) << 1) + ws, n & 31, acc[r] + bv[r]);
                            }
                        }
                    }
                }
            }
            if (t > 0) { // FC3+FC4 for t-1, h3(t-1) in AH3[rs]
                const int mt = wave, q = lane >> 4;
                float4 b3v = *(const float4*)(b3 + 4 * q);
                float4 w0v = *(const float4*)(W4 + 4 * q);
                float4 w1v = *(const float4*)(W4 + 16 + 4 * q);
                bf16x8 bb = *(const bf16x8*)(sb + O_AH3 + ((rs * 4 + mt) << 9) + (lane << 3));
                f32x4 acc = {0.f, 0.f, 0.f, 0.f};
                acc = MFMA(bF3, bb, acc, 0, 0, 0);
                float s0 = 0.f, s1 = 0.f;
#pragma unroll
                for (int r = 0; r < 4; ++r) {
                    float u = fmaxf(acc[r] + b3v[r], 0.0f);
                    s0 = fmaf(u, w0v[r], s0);
                    s1 = fmaf(u, w1v[r], s1);
                }
                s0 += __shfl_xor(s0, 16); s0 += __shfl_xor(s0, 32);
                s1 += __shfl_xor(s1, 16); s1 += __shfl_xor(s1, 32);
                if (lane < 16) {
                    float2 o; o.x = s0 + b4[0]; o.y = s1 + b4[1];
                    *(float2*)(out + (size_t)(b0 + (mt << 4) + lane) * 50 + (t - 1) * 2) = o;
                }
            }
        }
        __syncthreads();
    }

    // ---- epilogue: FC3+FC4 for t=24; h3(24) in AH3 slot 1 ----
    if (wave < 4) {
        const int mt = wave, q = lane >> 4;
        float4 b3v = *(const float4*)(b3 + 4 * q);
        float4 w0v = *(const float4*)(W4 + 4 * q);
        float4 w1v = *(const float4*)(W4 + 16 + 4 * q);
        bf16x8 bb = *(const bf16x8*)(sb + O_AH3 + ((4 + mt) << 9) + (lane << 3));
        f32x4 acc = {0.f, 0.f, 0.f, 0.f};
        acc = MFMA(bF3, bb, acc, 0, 0, 0);
        float s0 = 0.f, s1 = 0.f;
#pragma unroll
        for (int r = 0; r < 4; ++r) {
            float u = fmaxf(acc[r] + b3v[r], 0.0f);
            s0 = fmaf(u, w0v[r], s0);
            s1 = fmaf(u, w1v[r], s1);
        }
        s0 += __shfl_xor(s0, 16); s0 += __shfl_xor(s0, 32);
        s1 += __shfl_xor(s1, 16); s1 += __shfl_xor(s1, 32);
        if (lane < 16) {
            float2 o; o.x = s0 + b4[0]; o.y = s1 + b4[1];
            *(float2*)(out + (size_t)(b0 + (mt << 4) + lane) * 50 + 24 * 2) = o;
        }
    }
}

extern "C" void kernel_launch(void* const* d_in, const int* in_sizes, int n_in,
                              void* d_out, int out_size, void* d_ws, size_t ws_size,
                              hipStream_t stream) {
    (void)in_sizes; (void)n_in; (void)d_ws; (void)ws_size; (void)out_size;
    hipFuncSetAttribute((const void*)lstm_fused,
                        hipFuncAttributeMaxDynamicSharedMemorySize, LDS_BYTES);
    lstm_fused<<<dim3(2048), dim3(THREADS), LDS_BYTES, stream>>>(
        (const float*)d_in[0], (const float*)d_in[1],
        (const float*)d_in[2], (const float*)d_in[3],
        (const float*)d_in[4], (const float*)d_in[5],
        (const float*)d_in[6], (const float*)d_in[7],
        (const float*)d_in[8], (const float*)d_in[9],
        (const float*)d_in[10], (const float*)d_in[11],
        (const float*)d_in[12], (const float*)d_in[13],
        (const float*)d_in[14], (const float*)d_in[15],
        (const float*)d_in[16], (const float*)d_in[17],
        (const float*)d_in[18], (const float*)d_in[19],
        (const float*)d_in[20], (const float*)d_in[21],
        (float*)d_out);
}

// Round 9
// 1001.292 us; speedup vs baseline: 1.8281x; 1.2457x over previous
//
#include <hip/hip_runtime.h>
#include <hip/hip_bf16.h>

#define THREADS 768

typedef __hip_bfloat16 bf16;
typedef __attribute__((ext_vector_type(4))) float f32x4;
typedef __attribute__((ext_vector_type(8))) short bf16x8;

#define MFMA __builtin_amdgcn_mfma_f32_16x16x32_bf16

// ---- LDS layout (bf16 elems), blocks of 512 = one fragment tile (16 batch x 32 K)
// All buffers: read slot[p], write slot[q], p = t&1.
#define O_A1  0       // 2 slots x 4mt : K=[x(2)|h1(16)|k18=1|pad]
#define O_AY  4096    // 2 slots x 4mt x 2kc : K=[y(36)|k36=1|pad]
#define O_AT1 12288   // 2 slots x 4mt x 2kc : t1(64)
#define O_A2  20480   // 4mt x 10 chunks [kc*2+slot], K=[l2(72)|h2(72)|k144=1|pad]
#define O_AH3 40960   // 2 slots x 4mt : h3(32)
#define LDS_ELEMS 45056
#define LDS_BYTES (LDS_ELEMS * 2)   // 90112

// self-consistent K mapping within a fragment tile (verified rounds 1-8)
__device__ __forceinline__ int kmap(int l, int j) {
    return (((l >> 4) & 3) << 2) + (j & 3) + ((j >> 2) << 4);
}
__device__ __forceinline__ int frag_off(int m, int k) { // k in [0,32)
    int l = (m & 15) | (((k >> 2) & 3) << 4);
    int j = (k & 3) | (((k >> 4) & 1) << 2);
    return (l << 3) + j;
}
__device__ __forceinline__ void st_frag(bf16* sbase, int KC, int m, int k, float v) {
    sbase[(((m >> 4) * KC + (k >> 5)) << 9) + frag_off(m, k & 31)] = __float2bfloat16(v);
}
__device__ __forceinline__ void st_frag_c(bf16* sbase, int KC, int m, int cidx, int kl, float v) {
    sbase[(((m >> 4) * KC + cidx) << 9) + frag_off(m, kl)] = __float2bfloat16(v);
}

__device__ __forceinline__ float rcp_(float x) { return __builtin_amdgcn_rcpf(x); }

// swapped-operand gate EW: lane's acc = {i,f,g,o} preacts (bias MFMA-folded). 4 exp + 3 rcp.
__device__ __forceinline__ float lstm_ew1(f32x4 acc, float& cst) {
    float ei = __expf(-acc[0]);
    float ef = __expf(-acc[1]);
    float eg = __expf(2.0f * fminf(acc[2], 40.0f));
    float eo = __expf(-acc[3]);
    float c = rcp_(1.0f + ef) * cst + (eg - 1.0f) * rcp_((1.0f + ei) * (eg + 1.0f));
    cst = c;
    float ec = __expf(2.0f * fminf(c, 40.0f));
    return (ec - 1.0f) * rcp_((1.0f + eo) * (ec + 1.0f));
}

__device__ __forceinline__ ushort bfu(float f) {
    union { bf16 b; ushort u; } v; v.b = __float2bfloat16(f); return v.u;
}

template <typename F>
__device__ __forceinline__ bf16x8 mk_frag(int lane, F val) { // val(k), k in [0,32)
    union { bf16x8 v; bf16 h[8]; } u;
#pragma unroll
    for (int j = 0; j < 8; ++j) u.h[j] = __float2bfloat16(val(kmap(lane, j)));
    return u.v;
}

__global__ void __launch_bounds__(THREADS, 3)
lstm_fused(const float* __restrict__ x, const float* __restrict__ y,
           const float* __restrict__ Wih1, const float* __restrict__ Whh1,
           const float* __restrict__ bih1, const float* __restrict__ bhh1,
           const float* __restrict__ Wih2, const float* __restrict__ Whh2,
           const float* __restrict__ bih2, const float* __restrict__ bhh2,
           const float* __restrict__ Wih3, const float* __restrict__ Whh3,
           const float* __restrict__ bih3, const float* __restrict__ bhh3,
           const float* __restrict__ W1, const float* __restrict__ b1,
           const float* __restrict__ W2, const float* __restrict__ b2,
           const float* __restrict__ W3, const float* __restrict__ b3,
           const float* __restrict__ W4, const float* __restrict__ b4,
           float* __restrict__ out) {
    extern __shared__ char smem[];
    bf16* sb = (bf16*)smem;
    const int tid = threadIdx.x;
    const int wave = tid >> 6, lane = tid & 63, ln15 = lane & 15;
    const int b0 = blockIdx.x * 64;

    // ---- wave roles (single phase per step; all inputs from previous phases) ----
    // w0-3 : L2 heavy (nt 2w,2w+1) + FC2 (nt=w) + FC34 (mt=w)
    // w4-5 : L2 heavy (nt 2w,2w+1) + L3 (nt w-4)
    // w6   : L2 light (nt 12) + L3 (nt 2) + L1 (nt 0) + x-stage
    // w7   : L2 light (nt 13) + L3 (nt 3) + L1 (nt 1) + FC2-tail (nt 4)
    // w8-9 : L2 light (nt w+6) + L3 (nt w-4) + L1 (nt w-6) + FC1 (nt w-8)
    // w10-11: L2 light (nt w+6) + L3 (nt w-4) + FC1 (nt w-8) + y-stage
    const bool HEAVY = wave < 6;
    const int ntL2a = HEAVY ? 2 * wave : 6 + wave;

    bf16x8 bL2[2][5];
    bf16x8 bL1 = {};
    bf16x8 bF1[2] = {};
    bf16x8 bF2[2] = {};
    bf16x8 bL3[5] = {};
    bf16x8 bF3 = {};

    { // LSTM2: K=[l2 72|h2 72|bias@144|pad]
        auto fillL2 = [&](int nt, bf16x8* dst) {
            int R = (nt << 4) + ln15;
            int r = (R & 3) * 72 + (R >> 2);
            float bias = bih2[r] + bhh2[r];
#pragma unroll
            for (int kc = 0; kc < 5; ++kc)
                dst[kc] = mk_frag(lane, [&](int kl) {
                    int k = kc * 32 + kl;
                    return k < 72 ? Wih2[r * 72 + k]
                         : (k < 144 ? Whh2[r * 72 + (k - 72)]
                         : (k == 144 ? bias : 0.0f)); });
        };
        fillL2(ntL2a, bL2[0]);
        if (HEAVY) fillL2(2 * wave + 1, bL2[1]);
        else { bL2[1][0] = bL2[0][0]; bL2[1][1] = bL2[0][0]; bL2[1][2] = bL2[0][0];
               bL2[1][3] = bL2[0][0]; bL2[1][4] = bL2[0][0]; }
    }
    if (wave >= 6 && wave < 10) { // LSTM1: K=[x 2|h1 16|bias@18|pad]
        int R = ((wave - 6) << 4) + ln15;
        int r = (R & 3) * 16 + (R >> 2);
        float bias = bih1[r] + bhh1[r];
        bL1 = mk_frag(lane, [&](int k) {
            return k < 2 ? Wih1[r * 2 + k]
                 : (k < 18 ? Whh1[r * 16 + (k - 2)]
                 : (k == 18 ? bias : 0.0f)); });
    }
    if (wave >= 8) { // FC1 (nt = wave-8): K=[y 36|bias@36|pad]
        int n = ((wave - 8) << 4) + ln15;
        float bias = b1[n];
#pragma unroll
        for (int kc = 0; kc < 2; ++kc)
            bF1[kc] = mk_frag(lane, [&](int kl) {
                int k = kc * 32 + kl;
                return k < 36 ? W1[n * 36 + k] : (k == 36 ? bias : 0.0f); });
    }
    if (wave >= 4) { // LSTM3: A1-tile[h1|bias@18] ; A2 kc2,3,4 (h2) ; AH3 (h3)
        int R = ((wave - 4) << 4) + ln15;
        int r = (R & 3) * 32 + (R >> 2);
        float bias = bih3[r] + bhh3[r];
        bL3[0] = mk_frag(lane, [&](int k) {
            return (k >= 2 && k < 18) ? Wih3[r * 88 + (k - 2)] : (k == 18 ? bias : 0.0f); });
        bL3[1] = mk_frag(lane, [&](int k) {
            return (k >= 8) ? Wih3[r * 88 + 8 + k] : 0.0f; });
        bL3[2] = mk_frag(lane, [&](int k) { return Wih3[r * 88 + 40 + k]; });
        bL3[3] = mk_frag(lane, [&](int k) {
            return (k < 16) ? Wih3[r * 88 + 72 + k] : 0.0f; });
        bL3[4] = mk_frag(lane, [&](int k) { return Whh3[r * 32 + k]; });
    }
    if (wave < 4 || wave == 7) { // FC2
        int nt2 = (wave == 7) ? 4 : wave;
        int n = (nt2 << 4) + ln15;
#pragma unroll
        for (int kc = 0; kc < 2; ++kc)
            bF2[kc] = mk_frag(lane, [&](int kl) {
                return (n < 72) ? W2[n * 64 + kc * 32 + kl] : 0.0f; });
    }
    if (wave < 4) bF3 = mk_frag(lane, [&](int k) { return W3[ln15 * 32 + k]; });

    // ---- zero LDS ----
    {
        int4* z = (int4*)sb;
        int4 zv = {0, 0, 0, 0};
        for (int i = tid; i < LDS_BYTES / 16; i += THREADS) z[i] = zv;
    }
    __syncthreads();
    // ---- prologue stage: y(0)->AY[0], y(1)->AY[1], x(0)->A1[0], bias lanes ----
    for (int it = tid; it < 2 * 2304; it += THREADS) {
        int slot = it / 2304, r2 = it - slot * 2304;
        int m = r2 / 36, k = r2 - m * 36;
        st_frag(sb + O_AY + ((slot * 8) << 9), 2, m, k,
                y[(size_t)(b0 + m) * 900 + slot * 36 + k]);
    }
    if (tid < 128) {
        int m = tid >> 1, k = tid & 1;
        st_frag(sb + O_A1, 1, m, k, x[(size_t)(b0 + m) * 50 + k]);
    }
    {
        const bf16 one = __float2bfloat16(1.0f);
        if (tid < 128) { // A1 k=18, both slots
            int s = tid >> 6, mt = (tid >> 4) & 3, n = tid & 15;
            sb[O_A1 + ((s * 4 + mt) << 9) + frag_off(n, 18)] = one;
        } else if (tid < 256) { // AY k=36 (kc1, kl=4), both slots
            int i = tid - 128; int s = i >> 6, mt = (i >> 4) & 3, n = i & 15;
            sb[O_AY + ((s * 8 + mt * 2 + 1) << 9) + frag_off(n, 4)] = one;
        } else if (tid < 384) { // A2 k=144 (chunk 8+slot, kl=16), both slots
            int i = tid - 256; int s = i >> 6, mt = (i >> 4) & 3, n = i & 15;
            sb[O_A2 + ((mt * 10 + 8 + s) << 9) + frag_off(n, 16)] = one;
        }
    }
    __syncthreads();
    // ---- prologue FC1(0)->AT1[1], FC1(1)->AT1[0] on w8-11 ----
    if (wave >= 8) {
        const int nf0 = ((wave - 8) << 4) + ((lane >> 4) << 2);
#pragma unroll
        for (int s = 0; s < 2; ++s) {
#pragma unroll
            for (int mt = 0; mt < 4; ++mt) {
                f32x4 acc = {0.f, 0.f, 0.f, 0.f};
#pragma unroll
                for (int kc = 0; kc < 2; ++kc) {
                    bf16x8 a = *(const bf16x8*)(sb + O_AY + ((s * 8 + mt * 2 + kc) << 9) + (lane << 3));
                    acc = MFMA(bF1[kc], a, acc, 0, 0, 0);
                }
                int batch = (mt << 4) + ln15;
#pragma unroll
                for (int r = 0; r < 4; ++r)
                    st_frag(sb + O_AT1 + (((s ^ 1) * 8) << 9), 2, batch, nf0 + r, fmaxf(acc[r], 0.0f));
            }
        }
    }
    __syncthreads();
    // ---- prologue FC2(0)->A2 l2 slot0 (w0-3,w7); stage y(2)->AY[0] (w10-11) ----
    if (wave < 4 || wave == 7) {
        const int nt2 = (wave == 7) ? 4 : wave;
        const int nb = (nt2 << 4) + ((lane >> 4) << 2);
        float4 bv = {0.f, 0.f, 0.f, 0.f};
        if (nb < 72) bv = *(const float4*)(b2 + nb);
#pragma unroll
        for (int mt = 0; mt < 4; ++mt) {
            f32x4 acc = {0.f, 0.f, 0.f, 0.f};
#pragma unroll
            for (int kc = 0; kc < 2; ++kc) {
                bf16x8 a = *(const bf16x8*)(sb + O_AT1 + ((8 + mt * 2 + kc) << 9) + (lane << 3));
                acc = MFMA(bF2[kc], a, acc, 0, 0, 0);
            }
            if (nb < 72) {
                int batch = (mt << 4) + ln15;
#pragma unroll
                for (int r = 0; r < 4; ++r) {
                    int n = nb + r;
                    st_frag_c(sb + O_A2, 10, batch, ((n >> 5) << 1), n & 31, acc[r] + bv[r]);
                }
            }
        }
    } else if (wave >= 10) {
        const int m = ((wave - 10) << 5) + (lane >> 1);
        const int mt = m >> 4;
        const float* yp = y + (size_t)(b0 + m) * 900 + 2 * 36;
#pragma unroll
        for (int c = (lane & 1); c < 9; c += 2) {
            float4 v = *(const float4*)(yp + 4 * c);
            ushort4 pk;
            pk.x = bfu(v.x); pk.y = bfu(v.y); pk.z = bfu(v.z); pk.w = bfu(v.w);
            int k0 = 4 * c, kc = k0 >> 5;
            int l2v = (m & 15) | (((k0 >> 2) & 3) << 4);
            int j0 = ((k0 >> 4) & 1) << 2;
            *(ushort4*)((ushort*)(sb + O_AY) + ((mt * 2 + kc) << 9) + (l2v << 3) + j0) = pk;
        }
    }
    float c1[4] = {};
    float cs2[2][4] = {};
    float c3[4] = {};
    __syncthreads();

    // ======== main loop: ONE barrier per phase ========
    for (int t = 0; t <= 25; ++t) {
        const int p = t & 1, q = p ^ 1;

        // ---- LSTM2(t), all waves, t<=24 ----
        if (t <= 24) {
#pragma unroll
            for (int mt = 0; mt < 4; ++mt) {
                bf16x8 al[5];
#pragma unroll
                for (int b = 0; b < 5; ++b)
                    al[b] = *(const bf16x8*)(sb + O_A2 + ((mt * 10 + 2 * b + p) << 9) + (lane << 3));
                {
                    f32x4 acc = {0.f, 0.f, 0.f, 0.f};
#pragma unroll
                    for (int b = 0; b < 5; ++b) acc = MFMA(bL2[0][b], al[b], acc, 0, 0, 0);
                    float hv = lstm_ew1(acc, cs2[0][mt]);
                    int batch = (mt << 4) + ln15;
                    int k = 72 + (ntL2a << 2) + (lane >> 4);
                    st_frag_c(sb + O_A2, 10, batch, ((k >> 5) << 1) + q, k & 31, hv);
                }
                if (HEAVY) {
                    f32x4 acc = {0.f, 0.f, 0.f, 0.f};
#pragma unroll
                    for (int b = 0; b < 5; ++b) acc = MFMA(bL2[1][b], al[b], acc, 0, 0, 0);
                    float hv = lstm_ew1(acc, cs2[1][mt]);
                    int batch = (mt << 4) + ln15;
                    int k = 72 + ((2 * wave + 1) << 2) + (lane >> 4);
                    st_frag_c(sb + O_A2, 10, batch, ((k >> 5) << 1) + q, k & 31, hv);
                }
            }
        }

        // ---- LSTM1(t) on w6-9, t<=24 ----
        if (t <= 24 && wave >= 6 && wave < 10) {
            const int nt1 = wave - 6;
#pragma unroll
            for (int mt = 0; mt < 4; ++mt) {
                bf16x8 a = *(const bf16x8*)(sb + O_A1 + ((p * 4 + mt) << 9) + (lane << 3));
                f32x4 acc = {0.f, 0.f, 0.f, 0.f};
                acc = MFMA(bL1, a, acc, 0, 0, 0);
                float hv = lstm_ew1(acc, c1[mt]);
                int batch = (mt << 4) + ln15;
                st_frag(sb + O_A1 + ((q * 4) << 9), 1, batch, 2 + (nt1 << 2) + (lane >> 4), hv);
            }
        }
        // ---- x(t+1) stage on w6, t<=23 ----
        if (wave == 6 && t <= 23) {
            const int m = lane, mt = m >> 4;
            float2 xv = *(const float2*)(x + (size_t)(b0 + m) * 50 + (t + 1) * 2);
            union { uint u; ushort s[2]; } xu;
            xu.s[0] = bfu(xv.x); xu.s[1] = bfu(xv.y);
            *(uint*)((ushort*)(sb + O_A1) + ((q * 4 + mt) << 9) + ((m & 15) << 3)) = xu.u;
        }
        // ---- FC1(t+2) on w8-11, t<=22 ----
        if (t <= 22 && wave >= 8) {
            const int nf0 = ((wave - 8) << 4) + ((lane >> 4) << 2);
#pragma unroll
            for (int mt = 0; mt < 4; ++mt) {
                f32x4 acc = {0.f, 0.f, 0.f, 0.f};
#pragma unroll
                for (int kc = 0; kc < 2; ++kc) {
                    bf16x8 a = *(const bf16x8*)(sb + O_AY + ((p * 8 + mt * 2 + kc) << 9) + (lane << 3));
                    acc = MFMA(bF1[kc], a, acc, 0, 0, 0);
                }
                int batch = (mt << 4) + ln15;
#pragma unroll
                for (int r = 0; r < 4; ++r)
                    st_frag(sb + O_AT1 + ((q * 8) << 9), 2, batch, nf0 + r, fmaxf(acc[r], 0.0f));
            }
        }
        // ---- y(t+3) stage on w10-11, t<=21 ----
        if (wave >= 10 && t <= 21) {
            const int m = ((wave - 10) << 5) + (lane >> 1);
            const int mt = m >> 4;
            const float* yp = y + (size_t)(b0 + m) * 900 + (t + 3) * 36;
#pragma unroll
            for (int c = (lane & 1); c < 9; c += 2) {
                float4 v = *(const float4*)(yp + 4 * c);
                ushort4 pk;
                pk.x = bfu(v.x); pk.y = bfu(v.y); pk.z = bfu(v.z); pk.w = bfu(v.w);
                int k0 = 4 * c, kc = k0 >> 5;
                int l2v = (m & 15) | (((k0 >> 2) & 3) << 4);
                int j0 = ((k0 >> 4) & 1) << 2;
                *(ushort4*)((ushort*)(sb + O_AY) + ((q * 8 + mt * 2 + kc) << 9) + (l2v << 3) + j0) = pk;
            }
        }
        // ---- LSTM3(t-1) on w4-11, 1<=t<=25 ----
        if (t >= 1 && wave >= 4) {
            const int nt3 = wave - 4;
#pragma unroll
            for (int mt = 0; mt < 4; ++mt) {
                f32x4 acc = {0.f, 0.f, 0.f, 0.f};
                bf16x8 a0 = *(const bf16x8*)(sb + O_A1 + ((p * 4 + mt) << 9) + (lane << 3));
                acc = MFMA(bL3[0], a0, acc, 0, 0, 0);
#pragma unroll
                for (int j = 0; j < 3; ++j) {
                    bf16x8 a = *(const bf16x8*)(sb + O_A2 + ((mt * 10 + 4 + 2 * j + p) << 9) + (lane << 3));
                    acc = MFMA(bL3[1 + j], a, acc, 0, 0, 0);
                }
                bf16x8 a4 = *(const bf16x8*)(sb + O_AH3 + ((p * 4 + mt) << 9) + (lane << 3));
                acc = MFMA(bL3[4], a4, acc, 0, 0, 0);
                float hv = lstm_ew1(acc, c3[mt]);
                int batch = (mt << 4) + ln15;
                st_frag(sb + O_AH3 + ((q * 4) << 9), 1, batch, (nt3 << 2) + (lane >> 4), hv);
            }
        }
        // ---- FC2(t+1) on w0-3 & w7, t<=23 ----
        if (t <= 23 && (wave < 4 || wave == 7)) {
            const int nt2 = (wave == 7) ? 4 : wave;
            const int nb = (nt2 << 4) + ((lane >> 4) << 2);
            float4 bv = {0.f, 0.f, 0.f, 0.f};
            if (nb < 72) bv = *(const float4*)(b2 + nb);
#pragma unroll
            for (int mt = 0; mt < 4; ++mt) {
                f32x4 acc = {0.f, 0.f, 0.f, 0.f};
#pragma unroll
                for (int kc = 0; kc < 2; ++kc) {
                    bf16x8 a = *(const bf16x8*)(sb + O_AT1 + ((p * 8 + mt * 2 + kc) << 9) + (lane << 3));
                    acc = MFMA(bF2[kc], a, acc, 0, 0, 0);
                }
                if (nb < 72) {
                    int batch = (mt << 4) + ln15;
#pragma unroll
                    for (int r = 0; r < 4; ++r) {
                        int n = nb + r;
                        st_frag_c(sb + O_A2, 10, batch, ((n >> 5) << 1) + q, n & 31, acc[r] + bv[r]);
                    }
                }
            }
        }
        // ---- FC3+FC4(t-2) on w0-3, t>=2 ----
        if (t >= 2 && wave < 4) {
            const int mt = wave, qd = lane >> 4;
            float4 b3v = *(const float4*)(b3 + 4 * qd);
            float4 w0v = *(const float4*)(W4 + 4 * qd);
            float4 w1v = *(const float4*)(W4 + 16 + 4 * qd);
            bf16x8 bb = *(const bf16x8*)(sb + O_AH3 + ((p * 4 + mt) << 9) + (lane << 3));
            f32x4 acc = {0.f, 0.f, 0.f, 0.f};
            acc = MFMA(bF3, bb, acc, 0, 0, 0);
            float s0 = 0.f, s1 = 0.f;
#pragma unroll
            for (int r = 0; r < 4; ++r) {
                float u = fmaxf(acc[r] + b3v[r], 0.0f);
                s0 = fmaf(u, w0v[r], s0);
                s1 = fmaf(u, w1v[r], s1);
            }
            s0 += __shfl_xor(s0, 16); s0 += __shfl_xor(s0, 32);
            s1 += __shfl_xor(s1, 16); s1 += __shfl_xor(s1, 32);
            if (lane < 16) {
                float2 o; o.x = s0 + b4[0]; o.y = s1 + b4[1];
                *(float2*)(out + (size_t)(b0 + (mt << 4) + lane) * 50 + (t - 2) * 2) = o;
            }
        }
        __syncthreads();
    }

    // ---- epilogue: FC3+FC4 for t=24; h3(24) written phase 25 -> slot 0 ----
    if (wave < 4) {
        const int mt = wave, qd = lane >> 4;
        float4 b3v = *(const float4*)(b3 + 4 * qd);
        float4 w0v = *(const float4*)(W4 + 4 * qd);
        float4 w1v = *(const float4*)(W4 + 16 + 4 * qd);
        bf16x8 bb = *(const bf16x8*)(sb + O_AH3 + (mt << 9) + (lane << 3));
        f32x4 acc = {0.f, 0.f, 0.f, 0.f};
        acc = MFMA(bF3, bb, acc, 0, 0, 0);
        float s0 = 0.f, s1 = 0.f;
#pragma unroll
        for (int r = 0; r < 4; ++r) {
            float u = fmaxf(acc[r] + b3v[r], 0.0f);
            s0 = fmaf(u, w0v[r], s0);
            s1 = fmaf(u, w1v[r], s1);
        }
        s0 += __shfl_xor(s0, 16); s0 += __shfl_xor(s0, 32);
        s1 += __shfl_xor(s1, 16); s1 += __shfl_xor(s1, 32);
        if (lane < 16) {
            float2 o; o.x = s0 + b4[0]; o.y = s1 + b4[1];
            *(float2*)(out + (size_t)(b0 + (mt << 4) + lane) * 50 + 24 * 2) = o;
        }
    }
}

extern "C" void kernel_launch(void* const* d_in, const int* in_sizes, int n_in,
                              void* d_out, int out_size, void* d_ws, size_t ws_size,
                              hipStream_t stream) {
    (void)in_sizes; (void)n_in; (void)d_ws; (void)ws_size; (void)out_size;
    hipFuncSetAttribute((const void*)lstm_fused,
                        hipFuncAttributeMaxDynamicSharedMemorySize, LDS_BYTES);
    lstm_fused<<<dim3(2048), dim3(THREADS), LDS_BYTES, stream>>>(
        (const float*)d_in[0], (const float*)d_in[1],
        (const float*)d_in[2], (const float*)d_in[3],
        (const float*)d_in[4], (const float*)d_in[5],
        (const float*)d_in[6], (const float*)d_in[7],
        (const float*)d_in[8], (const float*)d_in[9],
        (const float*)d_in[10], (const float*)d_in[11],
        (const float*)d_in[12], (const float*)d_in[13],
        (const float*)d_in[14], (const float*)d_in[15],
        (const float*)d_in[16], (const float*)d_in[17],
        (const float*)d_in[18], (const float*)d_in[19],
        (const float*)d_in[20], (const float*)d_in[21],
        (float*)d_out);
}